// Round 3
// baseline (486.562 us; speedup 1.0000x reference)
//
#include <hip/hip_runtime.h>
#include <hip/hip_bf16.h>
#include <math.h>

#define HW 4096
#define SCALE 0.17677669529663687f
#define LOG2E 1.4426950408889634f

typedef __attribute__((ext_vector_type(8))) short short8;
typedef __attribute__((ext_vector_type(4))) float f32x4;
typedef __attribute__((ext_vector_type(4))) unsigned int u32x4;
typedef __attribute__((ext_vector_type(2))) unsigned int u32x2;

static __device__ __forceinline__ unsigned short bf16b(float f) {
  __hip_bfloat16 h = __float2bfloat16(f);
  return *reinterpret_cast<unsigned short*>(&h);
}

// ---- GEMM: Y[256][4096] = W @ X + b; f32 out / per-head bf16 (scaled) / flat bf16 ----
__global__ __launch_bounds__(256) void gemm256(const float* __restrict__ W,
                                               const float* __restrict__ bias,
                                               const float* __restrict__ X,
                                               float* __restrict__ Yf,
                                               unsigned short* __restrict__ Yt,
                                               unsigned short* __restrict__ Yv,
                                               float sc) {
  __shared__ float w_s[16][256];
  int tid = threadIdx.x;
  int o0 = (blockIdx.x >> 4) * 16;
  int p = (blockIdx.x & 15) * 256 + tid;
  #pragma unroll
  for (int i = 0; i < 16; ++i) w_s[i][tid] = W[(o0 + i) * 256 + tid];
  __syncthreads();
  float acc[16];
  #pragma unroll
  for (int i = 0; i < 16; ++i) acc[i] = 0.f;
  for (int c = 0; c < 256; ++c) {
    float xv = X[c * HW + p];
    #pragma unroll
    for (int i = 0; i < 16; ++i) acc[i] += w_s[i][c] * xv;
  }
  float r[16];
  #pragma unroll
  for (int i = 0; i < 16; ++i) r[i] = acc[i] + bias[o0 + i];
  if (Yf) {
    #pragma unroll
    for (int i = 0; i < 16; ++i) Yf[(o0 + i) * HW + p] = r[i];
  }
  if (Yt) {  // Yt[(h*4096+p)*32 + c], scaled
    int h = o0 >> 5, c0 = o0 & 31;
    unsigned int pk[8];
    #pragma unroll
    for (int j = 0; j < 8; ++j)
      pk[j] = (unsigned int)bf16b(r[2 * j] * sc) | ((unsigned int)bf16b(r[2 * j + 1] * sc) << 16);
    unsigned int* dst = (unsigned int*)(Yt + ((size_t)(h * HW + p) * 32 + c0));
    u32x4 lo4 = {pk[0], pk[1], pk[2], pk[3]};
    u32x4 hi4 = {pk[4], pk[5], pk[6], pk[7]};
    *(u32x4*)dst = lo4;
    *(u32x4*)(dst + 4) = hi4;
  }
  if (Yv) {
    #pragma unroll
    for (int i = 0; i < 16; ++i) Yv[(o0 + i) * HW + p] = bf16b(r[i]);
  }
}

// ---- depthwise 9x9 conv ----
__global__ __launch_bounds__(256) void dwconv_kernel(const float* __restrict__ q,
                                                     const float* __restrict__ wdw,
                                                     const float* __restrict__ bdw,
                                                     float* __restrict__ o) {
  int lane = threadIdx.x & 63;
  int wave = threadIdx.x >> 6;
  int bid = blockIdx.x;
  int y4 = bid & 15; int c = (bid >> 4) & 63; int g = bid >> 10;
  int y = y4 * 4 + wave;
  int x = lane;
  const float* qc = q + (g * 64 + c) * HW;
  float acc = bdw[c];
  #pragma unroll
  for (int ky = 0; ky < 9; ++ky) {
    int yy = y + ky - 4;
    if (yy < 0 || yy > 63) continue;
    #pragma unroll
    for (int kx = 0; kx < 9; ++kx) {
      int xx = x + kx - 4;
      if (xx < 0 || xx > 63) continue;
      acc += wdw[c * 81 + ky * 9 + kx] * qc[yy * 64 + xx];
    }
  }
  o[(g * 64 + c) * HW + y * 64 + x] = acc;
}

// ---- LN + GELU + pointwise + tanh -> pos (y,x) and padded-coord constants cxy ----
__global__ __launch_bounds__(256) void ln_offset_kernel(const float* __restrict__ o,
                                                        const float* __restrict__ ln_g,
                                                        const float* __restrict__ ln_b,
                                                        const float* __restrict__ wpw,
                                                        float* __restrict__ pos,
                                                        float* __restrict__ cxy) {
  int wave = threadIdx.x >> 6;
  int c = threadIdx.x & 63;
  int bid = blockIdx.x;
  int xc = bid & 15; int y = (bid >> 4) & 63; int g = bid >> 10;
  int x = xc * 4 + wave;
  int p = y * 64 + x;
  float v = o[(g * 64 + c) * HW + p];
  float s = v, s2 = v * v;
  #pragma unroll
  for (int m = 32; m; m >>= 1) { s += __shfl_xor(s, m); s2 += __shfl_xor(s2, m); }
  float mu = s * (1.f / 64.f);
  float var = s2 * (1.f / 64.f) - mu * mu;
  float nv = (v - mu) * rsqrtf(var + 1e-5f) * ln_g[c] + ln_b[c];
  nv = 0.5f * nv * (1.f + erff(nv * 0.70710678118654752f));
  float t0 = wpw[c] * nv, t1 = wpw[64 + c] * nv;
  #pragma unroll
  for (int m = 32; m; m >>= 1) { t0 += __shfl_xor(t0, m); t1 += __shfl_xor(t1, m); }
  if (c == 0) {
    float offy = tanhf(t0) * (2.0f / 64.0f);
    float offx = tanhf(t1) * (2.0f / 64.0f);
    float py = offy + (y + 0.5f) * (2.f / 64.f) - 1.f;
    float px = offx + (x + 0.5f) * (2.f / 64.f) - 1.f;
    pos[(g * HW + p) * 2 + 0] = py;
    pos[(g * HW + p) * 2 + 1] = px;
    // padded-table coords: gx = ex_m + cx_n with +1 border fold
    cxy[(g * HW + p) * 2 + 0] = 64.0f - 31.5f * px;
    cxy[(g * HW + p) * 2 + 1] = 64.0f - 31.5f * py;
  }
}

// ---- bilinear sample of x at pos -> xs[256][4096] ----
__global__ __launch_bounds__(256) void sample_kernel(const float* __restrict__ x,
                                                     const float* __restrict__ pos,
                                                     float* __restrict__ xs) {
  int bid = blockIdx.x;
  int cc = bid & 3; int nt = (bid >> 2) & 15; int g = bid >> 6;
  int n = nt * 256 + threadIdx.x;
  float py = pos[(g * HW + n) * 2 + 0];
  float px = pos[(g * HW + n) * 2 + 1];
  float gx = (px + 1.f) * 31.5f;
  float gy = (py + 1.f) * 31.5f;
  float xf = floorf(gx), yf = floorf(gy);
  int xi = (int)xf, yi = (int)yf;
  float fx = gx - xf, fy = gy - yf;
  int x0c = min(max(xi, 0), 63), x1c = min(max(xi + 1, 0), 63);
  int y0c = min(max(yi, 0), 63), y1c = min(max(yi + 1, 0), 63);
  float wx0 = ((unsigned)xi <= 63u) ? (1.f - fx) : 0.f;
  float wx1 = ((unsigned)(xi + 1) <= 63u) ? fx : 0.f;
  float wy0 = ((unsigned)yi <= 63u) ? (1.f - fy) : 0.f;
  float wy1 = ((unsigned)(yi + 1) <= 63u) ? fy : 0.f;
  #pragma unroll 4
  for (int ci = 0; ci < 16; ++ci) {
    int c = cc * 16 + ci;
    const float* xp = x + (g * 64 + c) * HW;
    float vsum = wy0 * (wx0 * xp[y0c * 64 + x0c] + wx1 * xp[y0c * 64 + x1c]) +
                 wy1 * (wx0 * xp[y1c * 64 + x0c] + wx1 * xp[y1c * 64 + x1c]);
    xs[(g * 64 + c) * HW + n] = vsum;
  }
}

// ---- build zero-padded, log2e-scaled RPE tables: pad[h][129][129] ----
__global__ __launch_bounds__(256) void build_rpe_kernel(const float* __restrict__ rpe,
                                                        float* __restrict__ pad) {
  int idx = blockIdx.x * 256 + threadIdx.x;
  if (idx >= 8 * 16641) return;
  int h = idx / 16641; int r = idx - h * 16641;
  int y = r / 129, x = r - y * 129;
  float v = 0.f;
  if (y > 0 && y < 128 && x > 0 && x < 128)
    v = rpe[h * 16129 + (y - 1) * 127 + (x - 1)] * LOG2E;
  pad[idx] = v;
}

// ---- per-head softmax update + PV MFMA ----
static __device__ __forceinline__ void head_update(const float sv[8], float& m_run, float& l_run,
                                                   f32x4& oA, f32x4& oB, short8 va, short8 vb,
                                                   unsigned int (*pp)[20], int lm, int lg) {
  float tmax = sv[0];
  #pragma unroll
  for (int i = 1; i < 8; ++i) tmax = fmaxf(tmax, sv[i]);
  tmax = fmaxf(tmax, __shfl_xor(tmax, 16));
  tmax = fmaxf(tmax, __shfl_xor(tmax, 32));
  float mnew = fmaxf(m_run, tmax);
  float alpha = __builtin_amdgcn_exp2f(m_run - mnew);
  float p[8]; float ps = 0.f;
  #pragma unroll
  for (int i = 0; i < 8; ++i) { p[i] = __builtin_amdgcn_exp2f(sv[i] - mnew); ps += p[i]; }
  ps += __shfl_xor(ps, 16);
  ps += __shfl_xor(ps, 32);
  l_run = l_run * alpha + ps;
  m_run = mnew;
  oA *= alpha;
  oB *= alpha;
  unsigned int w0 = (unsigned int)bf16b(p[0]) | ((unsigned int)bf16b(p[1]) << 16);
  unsigned int w1 = (unsigned int)bf16b(p[2]) | ((unsigned int)bf16b(p[3]) << 16);
  unsigned int w2 = (unsigned int)bf16b(p[4]) | ((unsigned int)bf16b(p[5]) << 16);
  unsigned int w3 = (unsigned int)bf16b(p[6]) | ((unsigned int)bf16b(p[7]) << 16);
  u32x2 wa = {w0, w1}, wb = {w2, w3};
  *(u32x2*)&pp[lm][2 * lg] = wa;       // n-pairs 2lg, 2lg+1   (n = 4lg+r, t0)
  *(u32x2*)&pp[lm][8 + 2 * lg] = wb;   // n-pairs 8+2lg, ...   (n = 16+4lg+r, t1)
  u32x4 pw = *(u32x4*)&pp[lm][4 * lg]; // n = 8lg .. 8lg+7
  union { u32x4 u; short8 s; } cv; cv.u = pw;
  oA = __builtin_amdgcn_mfma_f32_16x16x32_bf16(va, cv.s, oA, 0, 0, 0);
  oB = __builtin_amdgcn_mfma_f32_16x16x32_bf16(vb, cv.s, oB, 0, 0, 0);
}

// ---- fused attention: 2 heads (one group) per block, padded-table bias, exp2 softmax ----
__global__ __launch_bounds__(256) void attn_kernel(const unsigned short* __restrict__ qt,
                                                   const unsigned short* __restrict__ kt,
                                                   const unsigned short* __restrict__ vbuf,
                                                   const float* __restrict__ cxy,
                                                   const float* __restrict__ tpad,
                                                   float* __restrict__ att) {
  __shared__ __align__(16) unsigned int P_pack[2][4][16][20];
  __shared__ float red_m[2][4][16];
  __shared__ float red_l[2][4][16];
  __shared__ float red_acc[2][4][32][16];

  int tid = threadIdx.x;
  int w = tid >> 6;
  int l = tid & 63;
  int lm = l & 15;
  int lg = l >> 4;
  int g = blockIdx.x >> 8;
  int mt = blockIdx.x & 255;
  int m0 = mt * 16;
  int m = m0 + lm;
  int xm = m & 63, ym = m >> 6;
  float ex = (xm + 0.5f) * (63.0f / 64.0f) - 31.5f;
  float ey = (ym + 0.5f) * (63.0f / 64.0f) - 31.5f;
  int h0 = g * 2;
  const float* tab0 = tpad + (size_t)h0 * 16641;
  const float* tab1 = tab0 + 16641;
  const float* cbase = cxy + (size_t)g * HW * 2;

  short8 qf0 = *(const short8*)(qt + ((size_t)(h0 * HW + m) * 32 + 8 * lg));
  short8 qf1 = *(const short8*)(qt + ((size_t)((h0 + 1) * HW + m) * 32 + 8 * lg));

  f32x4 o0A = {0.f, 0.f, 0.f, 0.f}, o0B = {0.f, 0.f, 0.f, 0.f};
  f32x4 o1A = {0.f, 0.f, 0.f, 0.f}, o1B = {0.f, 0.f, 0.f, 0.f};
  float m0r = -3.0e38f, l0r = 0.f, m1r = -3.0e38f, l1r = 0.f;

  for (int it = 0; it < 32; ++it) {
    int n0 = (it * 4 + w) * 32;
    short8 k0a = *(const short8*)(kt + ((size_t)(h0 * HW + n0 + lm) * 32 + 8 * lg));
    short8 k0b = *(const short8*)(kt + ((size_t)(h0 * HW + n0 + 16 + lm) * 32 + 8 * lg));
    short8 k1a = *(const short8*)(kt + ((size_t)((h0 + 1) * HW + n0 + lm) * 32 + 8 * lg));
    short8 k1b = *(const short8*)(kt + ((size_t)((h0 + 1) * HW + n0 + 16 + lm) * 32 + 8 * lg));
    f32x4 z = {0.f, 0.f, 0.f, 0.f};
    f32x4 s0a = __builtin_amdgcn_mfma_f32_16x16x32_bf16(k0a, qf0, z, 0, 0, 0);
    f32x4 s0b = __builtin_amdgcn_mfma_f32_16x16x32_bf16(k0b, qf0, z, 0, 0, 0);
    f32x4 s1a = __builtin_amdgcn_mfma_f32_16x16x32_bf16(k1a, qf1, z, 0, 0, 0);
    f32x4 s1b = __builtin_amdgcn_mfma_f32_16x16x32_bf16(k1b, qf1, z, 0, 0, 0);
    short8 v0a = *(const short8*)(vbuf + ((size_t)(h0 * 32 + lm) * HW + n0 + 8 * lg));
    short8 v0b = *(const short8*)(vbuf + ((size_t)(h0 * 32 + 16 + lm) * HW + n0 + 8 * lg));
    short8 v1a = *(const short8*)(vbuf + ((size_t)((h0 + 1) * 32 + lm) * HW + n0 + 8 * lg));
    short8 v1b = *(const short8*)(vbuf + ((size_t)((h0 + 1) * 32 + 16 + lm) * HW + n0 + 8 * lg));

    float sv0[8], sv1[8];
    #pragma unroll
    for (int t = 0; t < 2; ++t) {
      #pragma unroll
      for (int r = 0; r < 4; ++r) {
        int nl = 16 * t + 4 * lg + r;
        float2 cc = *(const float2*)(cbase + (size_t)(n0 + nl) * 2);
        float gx = ex + cc.x, gy = ey + cc.y;   // padded coords, always in-bounds
        float xf = floorf(gx), yf = floorf(gy);
        float fx = gx - xf, fy = gy - yf;
        int ib = (int)yf * 129 + (int)xf;
        float a00 = tab0[ib], a01 = tab0[ib + 1], a10 = tab0[ib + 129], a11 = tab0[ib + 130];
        float b00 = tab1[ib], b01 = tab1[ib + 1], b10 = tab1[ib + 129], b11 = tab1[ib + 130];
        float ar0 = a00 + fx * (a01 - a00);
        float ar1 = a10 + fx * (a11 - a10);
        float br0 = b00 + fx * (b01 - b00);
        float br1 = b10 + fx * (b11 - b10);
        float qk0 = t ? s0b[r] : s0a[r];
        float qk1 = t ? s1b[r] : s1a[r];
        sv0[4 * t + r] = qk0 + (ar0 + fy * (ar1 - ar0));
        sv1[4 * t + r] = qk1 + (br0 + fy * (br1 - br0));
      }
    }
    head_update(sv0, m0r, l0r, o0A, o0B, v0a, v0b, P_pack[0][w], lm, lg);
    head_update(sv1, m1r, l1r, o1A, o1B, v1a, v1b, P_pack[1][w], lm, lg);
  }

  if (lg == 0) {
    red_m[0][w][lm] = m0r; red_l[0][w][lm] = l0r;
    red_m[1][w][lm] = m1r; red_l[1][w][lm] = l1r;
  }
  #pragma unroll
  for (int r = 0; r < 4; ++r) {
    red_acc[0][w][4 * lg + r][lm] = o0A[r];
    red_acc[0][w][16 + 4 * lg + r][lm] = o0B[r];
    red_acc[1][w][4 * lg + r][lm] = o1A[r];
    red_acc[1][w][16 + 4 * lg + r][lm] = o1B[r];
  }
  __syncthreads();
  #pragma unroll
  for (int rep = 0; rep < 8; ++rep) {
    int idx = tid + rep * 256;        // idx = hh*1024 + cl*16 + mm
    int hh = idx >> 10, cl = (idx >> 4) & 31, mm = idx & 15;
    float M = fmaxf(fmaxf(red_m[hh][0][mm], red_m[hh][1][mm]),
                    fmaxf(red_m[hh][2][mm], red_m[hh][3][mm]));
    float lsum = 0.f, osum = 0.f;
    #pragma unroll
    for (int ww = 0; ww < 4; ++ww) {
      float e = __builtin_amdgcn_exp2f(red_m[hh][ww][mm] - M);
      lsum += red_l[hh][ww][mm] * e;
      osum += red_acc[hh][ww][cl][mm] * e;
    }
    att[(size_t)((h0 + hh) * 32 + cl) * HW + m0 + mm] = osum / lsum;
  }
}

extern "C" void kernel_launch(void* const* d_in, const int* in_sizes, int n_in,
                              void* d_out, int out_size, void* d_ws, size_t ws_size,
                              hipStream_t stream) {
  const float* x    = (const float*)d_in[0];
  const float* wq   = (const float*)d_in[1];
  const float* bq   = (const float*)d_in[2];
  const float* wk   = (const float*)d_in[3];
  const float* bk   = (const float*)d_in[4];
  const float* wv   = (const float*)d_in[5];
  const float* bv   = (const float*)d_in[6];
  const float* wdw  = (const float*)d_in[7];
  const float* bdw  = (const float*)d_in[8];
  const float* lng  = (const float*)d_in[9];
  const float* lnb  = (const float*)d_in[10];
  const float* wpw  = (const float*)d_in[11];
  const float* rpe  = (const float*)d_in[12];
  const float* wout = (const float*)d_in[13];
  const float* bout = (const float*)d_in[14];
  float* out = (float*)d_out;

  float* ws = (float*)d_ws;
  float* q_f32 = ws;                                        // 4MB (reused as xs)
  float* o_f32 = ws + (1 << 20);                            // 4MB (reused as att)
  unsigned short* qt  = (unsigned short*)(ws + (2 << 20));  // 2MB
  unsigned short* ktp = (unsigned short*)(ws + (2 << 20) + (1 << 19) * 1);  // hmm explicit below
  // explicit float-offset layout:
  ktp = (unsigned short*)(ws + ((2 << 20) + (1 << 19)));    // 2MB at float-offset 2.5M
  unsigned short* vbp = (unsigned short*)(ws + (3 << 20));  // 2MB at 3M floats
  float* pos = ws + ((3 << 20) + (1 << 19));                // 128KB at 3.5M floats
  float* cxy = pos + 32768;                                 // 128KB
  float* tpad = cxy + 32768;                                // 8*16641*4 = 532KB

  gemm256<<<256, 256, 0, stream>>>(wq, bq, x, q_f32, qt, nullptr, SCALE * LOG2E);
  build_rpe_kernel<<<521, 256, 0, stream>>>(rpe, tpad);
  dwconv_kernel<<<4096, 256, 0, stream>>>(q_f32, wdw, bdw, o_f32);
  ln_offset_kernel<<<4096, 256, 0, stream>>>(o_f32, lng, lnb, wpw, pos, cxy);
  sample_kernel<<<256, 256, 0, stream>>>(x, pos, q_f32);    // q_f32 := xs
  gemm256<<<256, 256, 0, stream>>>(wk, bk, q_f32, nullptr, ktp, nullptr, 1.0f);
  gemm256<<<256, 256, 0, stream>>>(wv, bv, q_f32, nullptr, nullptr, vbp, 1.0f);
  attn_kernel<<<1024, 256, 0, stream>>>(qt, ktp, vbp, cxy, tpad, o_f32);  // o_f32 := att
  gemm256<<<256, 256, 0, stream>>>(wout, bout, o_f32, out, nullptr, nullptr, 1.0f);
}

// Round 4
// 448.252 us; speedup vs baseline: 1.0855x; 1.0855x over previous
//
#include <hip/hip_runtime.h>
#include <hip/hip_bf16.h>
#include <math.h>

#define HW 4096
#define SCALE 0.17677669529663687f
#define LOG2E 1.4426950408889634f

typedef __attribute__((ext_vector_type(8))) short short8;
typedef __attribute__((ext_vector_type(4))) float f32x4;
typedef __attribute__((ext_vector_type(4))) unsigned int u32x4;
typedef __attribute__((ext_vector_type(2))) unsigned int u32x2;

static __device__ __forceinline__ unsigned short bf16b(float f) {
  __hip_bfloat16 h = __float2bfloat16(f);
  return *reinterpret_cast<unsigned short*>(&h);
}

// ---- GEMM: Y[256][4096] = W @ X + b; f32 out / per-head bf16 (scaled) / flat bf16 ----
__global__ __launch_bounds__(256) void gemm256(const float* __restrict__ W,
                                               const float* __restrict__ bias,
                                               const float* __restrict__ X,
                                               float* __restrict__ Yf,
                                               unsigned short* __restrict__ Yt,
                                               unsigned short* __restrict__ Yv,
                                               float sc) {
  __shared__ float w_s[16][256];
  int tid = threadIdx.x;
  int o0 = (blockIdx.x >> 4) * 16;
  int p = (blockIdx.x & 15) * 256 + tid;
  #pragma unroll
  for (int i = 0; i < 16; ++i) w_s[i][tid] = W[(o0 + i) * 256 + tid];
  __syncthreads();
  float acc[16];
  #pragma unroll
  for (int i = 0; i < 16; ++i) acc[i] = 0.f;
  for (int c = 0; c < 256; ++c) {
    float xv = X[c * HW + p];
    #pragma unroll
    for (int i = 0; i < 16; ++i) acc[i] += w_s[i][c] * xv;
  }
  float r[16];
  #pragma unroll
  for (int i = 0; i < 16; ++i) r[i] = acc[i] + bias[o0 + i];
  if (Yf) {
    #pragma unroll
    for (int i = 0; i < 16; ++i) Yf[(o0 + i) * HW + p] = r[i];
  }
  if (Yt) {  // Yt[(h*4096+p)*32 + c], scaled
    int h = o0 >> 5, c0 = o0 & 31;
    unsigned int pk[8];
    #pragma unroll
    for (int j = 0; j < 8; ++j)
      pk[j] = (unsigned int)bf16b(r[2 * j] * sc) | ((unsigned int)bf16b(r[2 * j + 1] * sc) << 16);
    unsigned int* dst = (unsigned int*)(Yt + ((size_t)(h * HW + p) * 32 + c0));
    u32x4 lo4 = {pk[0], pk[1], pk[2], pk[3]};
    u32x4 hi4 = {pk[4], pk[5], pk[6], pk[7]};
    *(u32x4*)dst = lo4;
    *(u32x4*)(dst + 4) = hi4;
  }
  if (Yv) {
    #pragma unroll
    for (int i = 0; i < 16; ++i) Yv[(o0 + i) * HW + p] = bf16b(r[i]);
  }
}

// ---- depthwise 9x9 conv ----
__global__ __launch_bounds__(256) void dwconv_kernel(const float* __restrict__ q,
                                                     const float* __restrict__ wdw,
                                                     const float* __restrict__ bdw,
                                                     float* __restrict__ o) {
  int lane = threadIdx.x & 63;
  int wave = threadIdx.x >> 6;
  int bid = blockIdx.x;
  int y4 = bid & 15; int c = (bid >> 4) & 63; int g = bid >> 10;
  int y = y4 * 4 + wave;
  int x = lane;
  const float* qc = q + (g * 64 + c) * HW;
  float acc = bdw[c];
  #pragma unroll
  for (int ky = 0; ky < 9; ++ky) {
    int yy = y + ky - 4;
    if (yy < 0 || yy > 63) continue;
    #pragma unroll
    for (int kx = 0; kx < 9; ++kx) {
      int xx = x + kx - 4;
      if (xx < 0 || xx > 63) continue;
      acc += wdw[c * 81 + ky * 9 + kx] * qc[yy * 64 + xx];
    }
  }
  o[(g * 64 + c) * HW + y * 64 + x] = acc;
}

// ---- LN + GELU + pointwise + tanh -> pos (y,x) and padded-coord constants cxy ----
__global__ __launch_bounds__(256) void ln_offset_kernel(const float* __restrict__ o,
                                                        const float* __restrict__ ln_g,
                                                        const float* __restrict__ ln_b,
                                                        const float* __restrict__ wpw,
                                                        float* __restrict__ pos,
                                                        float* __restrict__ cxy) {
  int wave = threadIdx.x >> 6;
  int c = threadIdx.x & 63;
  int bid = blockIdx.x;
  int xc = bid & 15; int y = (bid >> 4) & 63; int g = bid >> 10;
  int x = xc * 4 + wave;
  int p = y * 64 + x;
  float v = o[(g * 64 + c) * HW + p];
  float s = v, s2 = v * v;
  #pragma unroll
  for (int m = 32; m; m >>= 1) { s += __shfl_xor(s, m); s2 += __shfl_xor(s2, m); }
  float mu = s * (1.f / 64.f);
  float var = s2 * (1.f / 64.f) - mu * mu;
  float nv = (v - mu) * rsqrtf(var + 1e-5f) * ln_g[c] + ln_b[c];
  nv = 0.5f * nv * (1.f + erff(nv * 0.70710678118654752f));
  float t0 = wpw[c] * nv, t1 = wpw[64 + c] * nv;
  #pragma unroll
  for (int m = 32; m; m >>= 1) { t0 += __shfl_xor(t0, m); t1 += __shfl_xor(t1, m); }
  if (c == 0) {
    float offy = tanhf(t0) * (2.0f / 64.0f);
    float offx = tanhf(t1) * (2.0f / 64.0f);
    float py = offy + (y + 0.5f) * (2.f / 64.f) - 1.f;
    float px = offx + (x + 0.5f) * (2.f / 64.f) - 1.f;
    pos[(g * HW + p) * 2 + 0] = py;
    pos[(g * HW + p) * 2 + 1] = px;
    // padded-table coords: gx = ex_m + cx_n with +1 border fold
    cxy[(g * HW + p) * 2 + 0] = 64.0f - 31.5f * px;
    cxy[(g * HW + p) * 2 + 1] = 64.0f - 31.5f * py;
  }
}

// ---- bilinear sample of x at pos -> xs[256][4096] ----
__global__ __launch_bounds__(256) void sample_kernel(const float* __restrict__ x,
                                                     const float* __restrict__ pos,
                                                     float* __restrict__ xs) {
  int bid = blockIdx.x;
  int cc = bid & 3; int nt = (bid >> 2) & 15; int g = bid >> 6;
  int n = nt * 256 + threadIdx.x;
  float py = pos[(g * HW + n) * 2 + 0];
  float px = pos[(g * HW + n) * 2 + 1];
  float gx = (px + 1.f) * 31.5f;
  float gy = (py + 1.f) * 31.5f;
  float xf = floorf(gx), yf = floorf(gy);
  int xi = (int)xf, yi = (int)yf;
  float fx = gx - xf, fy = gy - yf;
  int x0c = min(max(xi, 0), 63), x1c = min(max(xi + 1, 0), 63);
  int y0c = min(max(yi, 0), 63), y1c = min(max(yi + 1, 0), 63);
  float wx0 = ((unsigned)xi <= 63u) ? (1.f - fx) : 0.f;
  float wx1 = ((unsigned)(xi + 1) <= 63u) ? fx : 0.f;
  float wy0 = ((unsigned)yi <= 63u) ? (1.f - fy) : 0.f;
  float wy1 = ((unsigned)(yi + 1) <= 63u) ? fy : 0.f;
  #pragma unroll 4
  for (int ci = 0; ci < 16; ++ci) {
    int c = cc * 16 + ci;
    const float* xp = x + (g * 64 + c) * HW;
    float vsum = wy0 * (wx0 * xp[y0c * 64 + x0c] + wx1 * xp[y0c * 64 + x1c]) +
                 wy1 * (wx0 * xp[y1c * 64 + x0c] + wx1 * xp[y1c * 64 + x1c]);
    xs[(g * 64 + c) * HW + n] = vsum;
  }
}

// ---- build zero-padded, log2e-scaled RPE tables: pad[h][129][129] ----
__global__ __launch_bounds__(256) void build_rpe_kernel(const float* __restrict__ rpe,
                                                        float* __restrict__ pad) {
  int idx = blockIdx.x * 256 + threadIdx.x;
  if (idx >= 8 * 16641) return;
  int h = idx / 16641; int r = idx - h * 16641;
  int y = r / 129, x = r - y * 129;
  float v = 0.f;
  if (y > 0 && y < 128 && x > 0 && x < 128)
    v = rpe[h * 16129 + (y - 1) * 127 + (x - 1)] * LOG2E;
  pad[idx] = v;
}

// ---- fused attention: 1 head per block (grid 2048), padded-table bias, exp2 softmax ----
__global__ __launch_bounds__(256) void attn_kernel(const unsigned short* __restrict__ qt,
                                                   const unsigned short* __restrict__ kt,
                                                   const unsigned short* __restrict__ vbuf,
                                                   const float* __restrict__ cxy,
                                                   const float* __restrict__ tpad,
                                                   float* __restrict__ att) {
  __shared__ __align__(16) unsigned int P_pack[4][16][20];
  __shared__ float red_m[4][16];
  __shared__ float red_l[4][16];
  __shared__ float red_acc[4][32][16];

  int tid = threadIdx.x;
  int w = tid >> 6;
  int l = tid & 63;
  int lm = l & 15;   // column: query m
  int lg = l >> 4;   // lane group
  int h = blockIdx.x >> 8;
  int mt = blockIdx.x & 255;
  int m0 = mt * 16;
  int m = m0 + lm;
  int xm = m & 63, ym = m >> 6;
  float ex = (xm + 0.5f) * (63.0f / 64.0f) - 31.5f;
  float ey = (ym + 0.5f) * (63.0f / 64.0f) - 31.5f;
  const float* tab = tpad + (size_t)h * 16641;
  const float* cbase = cxy + (size_t)(h >> 1) * HW * 2;

  short8 qf = *(const short8*)(qt + ((size_t)(h * HW + m) * 32 + 8 * lg));

  f32x4 oA = {0.f, 0.f, 0.f, 0.f};
  f32x4 oB = {0.f, 0.f, 0.f, 0.f};
  float m_run = -3.0e38f, l_run = 0.f;

  for (int it = 0; it < 32; ++it) {
    int n0 = (it * 4 + w) * 32;
    short8 ka = *(const short8*)(kt + ((size_t)(h * HW + n0 + lm) * 32 + 8 * lg));
    short8 kb = *(const short8*)(kt + ((size_t)(h * HW + n0 + 16 + lm) * 32 + 8 * lg));
    f32x4 z = {0.f, 0.f, 0.f, 0.f};
    f32x4 s0 = __builtin_amdgcn_mfma_f32_16x16x32_bf16(ka, qf, z, 0, 0, 0);
    f32x4 s1 = __builtin_amdgcn_mfma_f32_16x16x32_bf16(kb, qf, z, 0, 0, 0);
    short8 va = *(const short8*)(vbuf + ((size_t)(h * 32 + lm) * HW + n0 + 8 * lg));
    short8 vb = *(const short8*)(vbuf + ((size_t)(h * 32 + 16 + lm) * HW + n0 + 8 * lg));

    float sv[8];
    #pragma unroll
    for (int t = 0; t < 2; ++t) {
      #pragma unroll
      for (int r = 0; r < 4; ++r) {
        int nl = 16 * t + 4 * lg + r;
        float2 cc = *(const float2*)(cbase + (size_t)(n0 + nl) * 2);
        float gx = ex + cc.x, gy = ey + cc.y;   // padded coords, always in-bounds
        float xf = floorf(gx), yf = floorf(gy);
        float fx = gx - xf, fy = gy - yf;
        int ib = (int)yf * 129 + (int)xf;
        float2 a0 = *(const float2*)(tab + ib);        // a00, a01
        float2 a1 = *(const float2*)(tab + ib + 129);  // a10, a11
        float ar0 = a0.x + fx * (a0.y - a0.x);
        float ar1 = a1.x + fx * (a1.y - a1.x);
        float qk = t ? s1[r] : s0[r];
        sv[4 * t + r] = qk + (ar0 + fy * (ar1 - ar0));
      }
    }
    // column (per-m) softmax over this 32-n tile
    float tmax = sv[0];
    #pragma unroll
    for (int i = 1; i < 8; ++i) tmax = fmaxf(tmax, sv[i]);
    tmax = fmaxf(tmax, __shfl_xor(tmax, 16));
    tmax = fmaxf(tmax, __shfl_xor(tmax, 32));
    float mnew = fmaxf(m_run, tmax);
    float alpha = __builtin_amdgcn_exp2f(m_run - mnew);
    float p[8]; float ps = 0.f;
    #pragma unroll
    for (int i = 0; i < 8; ++i) { p[i] = __builtin_amdgcn_exp2f(sv[i] - mnew); ps += p[i]; }
    ps += __shfl_xor(ps, 16);
    ps += __shfl_xor(ps, 32);
    l_run = l_run * alpha + ps;
    m_run = mnew;
    oA *= alpha;
    oB *= alpha;
    unsigned int w0 = (unsigned int)bf16b(p[0]) | ((unsigned int)bf16b(p[1]) << 16);
    unsigned int w1 = (unsigned int)bf16b(p[2]) | ((unsigned int)bf16b(p[3]) << 16);
    unsigned int w2 = (unsigned int)bf16b(p[4]) | ((unsigned int)bf16b(p[5]) << 16);
    unsigned int w3 = (unsigned int)bf16b(p[6]) | ((unsigned int)bf16b(p[7]) << 16);
    u32x2 wa = {w0, w1}, wb = {w2, w3};
    *(u32x2*)&P_pack[w][lm][2 * lg] = wa;
    *(u32x2*)&P_pack[w][lm][8 + 2 * lg] = wb;
    u32x4 pw = *(u32x4*)&P_pack[w][lm][4 * lg];
    union { u32x4 u; short8 s; } cv; cv.u = pw;
    oA = __builtin_amdgcn_mfma_f32_16x16x32_bf16(va, cv.s, oA, 0, 0, 0);
    oB = __builtin_amdgcn_mfma_f32_16x16x32_bf16(vb, cv.s, oB, 0, 0, 0);
  }

  if (lg == 0) { red_m[w][lm] = m_run; red_l[w][lm] = l_run; }
  #pragma unroll
  for (int r = 0; r < 4; ++r) {
    red_acc[w][4 * lg + r][lm] = oA[r];
    red_acc[w][16 + 4 * lg + r][lm] = oB[r];
  }
  __syncthreads();
  #pragma unroll
  for (int rep = 0; rep < 2; ++rep) {
    int idx = tid + rep * 256;
    int cl = idx >> 4, mm = idx & 15;
    float M = fmaxf(fmaxf(red_m[0][mm], red_m[1][mm]), fmaxf(red_m[2][mm], red_m[3][mm]));
    float lsum = 0.f, osum = 0.f;
    #pragma unroll
    for (int ww = 0; ww < 4; ++ww) {
      float e = __builtin_amdgcn_exp2f(red_m[ww][mm] - M);
      lsum += red_l[ww][mm] * e;
      osum += red_acc[ww][cl][mm] * e;
    }
    att[(size_t)(h * 32 + cl) * HW + m0 + mm] = osum / lsum;
  }
}

extern "C" void kernel_launch(void* const* d_in, const int* in_sizes, int n_in,
                              void* d_out, int out_size, void* d_ws, size_t ws_size,
                              hipStream_t stream) {
  const float* x    = (const float*)d_in[0];
  const float* wq   = (const float*)d_in[1];
  const float* bq   = (const float*)d_in[2];
  const float* wk   = (const float*)d_in[3];
  const float* bk   = (const float*)d_in[4];
  const float* wv   = (const float*)d_in[5];
  const float* bv   = (const float*)d_in[6];
  const float* wdw  = (const float*)d_in[7];
  const float* bdw  = (const float*)d_in[8];
  const float* lng  = (const float*)d_in[9];
  const float* lnb  = (const float*)d_in[10];
  const float* wpw  = (const float*)d_in[11];
  const float* rpe  = (const float*)d_in[12];
  const float* wout = (const float*)d_in[13];
  const float* bout = (const float*)d_in[14];
  float* out = (float*)d_out;

  float* ws = (float*)d_ws;
  float* q_f32 = ws;                                        // 4MB (reused as xs)
  float* o_f32 = ws + (1 << 20);                            // 4MB (reused as att)
  unsigned short* qt  = (unsigned short*)(ws + (2 << 20));  // 2MB
  unsigned short* ktp = (unsigned short*)(ws + ((2 << 20) + (1 << 19)));  // 2MB
  unsigned short* vbp = (unsigned short*)(ws + (3 << 20));  // 2MB
  float* pos = ws + ((3 << 20) + (1 << 19));                // 128KB
  float* cxy = pos + 32768;                                 // 128KB
  float* tpad = cxy + 32768;                                // 532KB

  gemm256<<<256, 256, 0, stream>>>(wq, bq, x, q_f32, qt, nullptr, SCALE * LOG2E);
  build_rpe_kernel<<<521, 256, 0, stream>>>(rpe, tpad);
  dwconv_kernel<<<4096, 256, 0, stream>>>(q_f32, wdw, bdw, o_f32);
  ln_offset_kernel<<<4096, 256, 0, stream>>>(o_f32, lng, lnb, wpw, pos, cxy);
  sample_kernel<<<256, 256, 0, stream>>>(x, pos, q_f32);    // q_f32 := xs
  gemm256<<<256, 256, 0, stream>>>(wk, bk, q_f32, nullptr, ktp, nullptr, 1.0f);
  gemm256<<<256, 256, 0, stream>>>(wv, bv, q_f32, nullptr, nullptr, vbp, 1.0f);
  attn_kernel<<<2048, 256, 0, stream>>>(qt, ktp, vbp, cxy, tpad, o_f32);  // o_f32 := att
  gemm256<<<256, 256, 0, stream>>>(wout, bout, o_f32, out, nullptr, nullptr, 1.0f);
}

// Round 5
// 372.516 us; speedup vs baseline: 1.3062x; 1.2033x over previous
//
#include <hip/hip_runtime.h>
#include <hip/hip_bf16.h>
#include <math.h>

#define HW 4096
#define SCALE 0.17677669529663687f
#define LOG2E 1.4426950408889634f

typedef __attribute__((ext_vector_type(8))) short short8;
typedef __attribute__((ext_vector_type(4))) float f32x4;
typedef __attribute__((ext_vector_type(4), aligned(4))) float f32x4u;
typedef __attribute__((ext_vector_type(4))) unsigned int u32x4;
typedef __attribute__((ext_vector_type(2))) unsigned int u32x2;

static __device__ __forceinline__ unsigned short bf16b(float f) {
  __hip_bfloat16 h = __float2bfloat16(f);
  return *reinterpret_cast<unsigned short*>(&h);
}

// ---- GEMM: Y[256][4096] = W @ X + b. W via scalar (s_load) path, X via float2.
// o-tile 8, 2 p per thread, grid 256 blocks.
__global__ __launch_bounds__(256) void gemm256(const float* __restrict__ W,
                                               const float* __restrict__ bias,
                                               const float* __restrict__ X,
                                               float* __restrict__ Yf,
                                               unsigned short* __restrict__ Yt,
                                               unsigned short* __restrict__ Yv,
                                               float sc) {
  int tid = threadIdx.x;
  int o0 = (blockIdx.x >> 3) * 8;         // 32 o-tiles of 8
  int p = (blockIdx.x & 7) * 512 + tid * 2;  // 8 p-tiles of 512
  const float* Wb = W + o0 * 256;
  float ax[8], ay[8];
  #pragma unroll
  for (int i = 0; i < 8; ++i) { ax[i] = 0.f; ay[i] = 0.f; }
  #pragma unroll 4
  for (int c = 0; c < 256; ++c) {
    float2 xv = *(const float2*)(X + c * HW + p);
    #pragma unroll
    for (int i = 0; i < 8; ++i) {
      float wv = Wb[i * 256 + c];   // wave-uniform -> s_load, SGPR operand
      ax[i] += wv * xv.x;
      ay[i] += wv * xv.y;
    }
  }
  float rx[8], ry[8];
  #pragma unroll
  for (int i = 0; i < 8; ++i) {
    float b = bias[o0 + i];
    rx[i] = ax[i] + b;
    ry[i] = ay[i] + b;
  }
  if (Yf) {
    #pragma unroll
    for (int i = 0; i < 8; ++i) {
      float2 st = {rx[i], ry[i]};
      *(float2*)(Yf + (size_t)(o0 + i) * HW + p) = st;
    }
  }
  if (Yt) {  // Yt[(h*4096+p)*32 + c], scaled bf16
    int h = o0 >> 5, c0 = o0 & 31;
    u32x4 pk0, pk1;
    #pragma unroll
    for (int j = 0; j < 4; ++j) {
      pk0[j] = (unsigned int)bf16b(rx[2 * j] * sc) | ((unsigned int)bf16b(rx[2 * j + 1] * sc) << 16);
      pk1[j] = (unsigned int)bf16b(ry[2 * j] * sc) | ((unsigned int)bf16b(ry[2 * j + 1] * sc) << 16);
    }
    *(u32x4*)(Yt + ((size_t)(h * HW + p) * 32 + c0)) = pk0;
    *(u32x4*)(Yt + ((size_t)(h * HW + p + 1) * 32 + c0)) = pk1;
  }
  if (Yv) {  // flat bf16 [c][p]
    #pragma unroll
    for (int i = 0; i < 8; ++i) {
      unsigned int pk = (unsigned int)bf16b(rx[i]) | ((unsigned int)bf16b(ry[i]) << 16);
      *(unsigned int*)(Yv + (size_t)(o0 + i) * HW + p) = pk;
    }
  }
}

// ---- depthwise 9x9 conv ----
__global__ __launch_bounds__(256) void dwconv_kernel(const float* __restrict__ q,
                                                     const float* __restrict__ wdw,
                                                     const float* __restrict__ bdw,
                                                     float* __restrict__ o) {
  int lane = threadIdx.x & 63;
  int wave = threadIdx.x >> 6;
  int bid = blockIdx.x;
  int y4 = bid & 15; int c = (bid >> 4) & 63; int g = bid >> 10;
  int y = y4 * 4 + wave;
  int x = lane;
  const float* qc = q + (g * 64 + c) * HW;
  float acc = bdw[c];
  #pragma unroll
  for (int ky = 0; ky < 9; ++ky) {
    int yy = y + ky - 4;
    if (yy < 0 || yy > 63) continue;
    #pragma unroll
    for (int kx = 0; kx < 9; ++kx) {
      int xx = x + kx - 4;
      if (xx < 0 || xx > 63) continue;
      acc += wdw[c * 81 + ky * 9 + kx] * qc[yy * 64 + xx];
    }
  }
  o[(g * 64 + c) * HW + y * 64 + x] = acc;
}

// ---- LN + GELU + pointwise + tanh -> pos (y,x) and padded-coord constants cxy ----
__global__ __launch_bounds__(256) void ln_offset_kernel(const float* __restrict__ o,
                                                        const float* __restrict__ ln_g,
                                                        const float* __restrict__ ln_b,
                                                        const float* __restrict__ wpw,
                                                        float* __restrict__ pos,
                                                        float* __restrict__ cxy) {
  int wave = threadIdx.x >> 6;
  int c = threadIdx.x & 63;
  int bid = blockIdx.x;
  int xc = bid & 15; int y = (bid >> 4) & 63; int g = bid >> 10;
  int x = xc * 4 + wave;
  int p = y * 64 + x;
  float v = o[(g * 64 + c) * HW + p];
  float s = v, s2 = v * v;
  #pragma unroll
  for (int m = 32; m; m >>= 1) { s += __shfl_xor(s, m); s2 += __shfl_xor(s2, m); }
  float mu = s * (1.f / 64.f);
  float var = s2 * (1.f / 64.f) - mu * mu;
  float nv = (v - mu) * rsqrtf(var + 1e-5f) * ln_g[c] + ln_b[c];
  nv = 0.5f * nv * (1.f + erff(nv * 0.70710678118654752f));
  float t0 = wpw[c] * nv, t1 = wpw[64 + c] * nv;
  #pragma unroll
  for (int m = 32; m; m >>= 1) { t0 += __shfl_xor(t0, m); t1 += __shfl_xor(t1, m); }
  if (c == 0) {
    float offy = tanhf(t0) * (2.0f / 64.0f);
    float offx = tanhf(t1) * (2.0f / 64.0f);
    float py = offy + (y + 0.5f) * (2.f / 64.f) - 1.f;
    float px = offx + (x + 0.5f) * (2.f / 64.f) - 1.f;
    pos[(g * HW + p) * 2 + 0] = py;
    pos[(g * HW + p) * 2 + 1] = px;
    // padded-table coords: gx = ex_m + cx_n with +1 border fold
    cxy[(g * HW + p) * 2 + 0] = 64.0f - 31.5f * px;
    cxy[(g * HW + p) * 2 + 1] = 64.0f - 31.5f * py;
  }
}

// ---- bilinear sample of x at pos -> xs[256][4096] ----
__global__ __launch_bounds__(256) void sample_kernel(const float* __restrict__ x,
                                                     const float* __restrict__ pos,
                                                     float* __restrict__ xs) {
  int bid = blockIdx.x;
  int cc = bid & 3; int nt = (bid >> 2) & 15; int g = bid >> 6;
  int n = nt * 256 + threadIdx.x;
  float py = pos[(g * HW + n) * 2 + 0];
  float px = pos[(g * HW + n) * 2 + 1];
  float gx = (px + 1.f) * 31.5f;
  float gy = (py + 1.f) * 31.5f;
  float xf = floorf(gx), yf = floorf(gy);
  int xi = (int)xf, yi = (int)yf;
  float fx = gx - xf, fy = gy - yf;
  int x0c = min(max(xi, 0), 63), x1c = min(max(xi + 1, 0), 63);
  int y0c = min(max(yi, 0), 63), y1c = min(max(yi + 1, 0), 63);
  float wx0 = ((unsigned)xi <= 63u) ? (1.f - fx) : 0.f;
  float wx1 = ((unsigned)(xi + 1) <= 63u) ? fx : 0.f;
  float wy0 = ((unsigned)yi <= 63u) ? (1.f - fy) : 0.f;
  float wy1 = ((unsigned)(yi + 1) <= 63u) ? fy : 0.f;
  #pragma unroll 4
  for (int ci = 0; ci < 16; ++ci) {
    int c = cc * 16 + ci;
    const float* xp = x + (g * 64 + c) * HW;
    float vsum = wy0 * (wx0 * xp[y0c * 64 + x0c] + wx1 * xp[y0c * 64 + x1c]) +
                 wy1 * (wx0 * xp[y1c * 64 + x0c] + wx1 * xp[y1c * 64 + x1c]);
    xs[(g * 64 + c) * HW + n] = vsum;
  }
}

// ---- build interleaved-row, zero-padded, log2e-scaled RPE tables:
// tab2[h][y][x] = { pad(y,x), pad(y+1,x) }, y,x in [0,128]; pad(y,x) = rpe[y-1][x-1]*LOG2E inside.
__global__ __launch_bounds__(256) void build_rpe2_kernel(const float* __restrict__ rpe,
                                                         float* __restrict__ tab2) {
  int idx = blockIdx.x * 256 + threadIdx.x;
  if (idx >= 8 * 16641) return;
  int h = idx / 16641; int r = idx - h * 16641;
  int y = r / 129, x = r - y * 129;
  float v0 = 0.f, v1 = 0.f;
  if (x >= 1 && x <= 127) {
    if (y >= 1 && y <= 127) v0 = rpe[(h * 127 + (y - 1)) * 127 + (x - 1)] * LOG2E;
    if (y + 1 >= 1 && y + 1 <= 127) v1 = rpe[(h * 127 + y) * 127 + (x - 1)] * LOG2E;
  }
  float2 v = {v0, v1};
  *(float2*)(tab2 + (size_t)idx * 2) = v;
}

// ---- fused attention: 1 head per block, packed-corner gather, exp2 softmax ----
__global__ __launch_bounds__(256, 8) void attn_kernel(const unsigned short* __restrict__ qt,
                                                      const unsigned short* __restrict__ kt,
                                                      const unsigned short* __restrict__ vbuf,
                                                      const float* __restrict__ cxy,
                                                      const float* __restrict__ tpad2,
                                                      float* __restrict__ att) {
  __shared__ __align__(16) unsigned int P_pack[4][16][20];
  __shared__ float red_m[4][16];
  __shared__ float red_l[4][16];
  __shared__ float red_acc[4][32][16];

  int tid = threadIdx.x;
  int w = tid >> 6;
  int l = tid & 63;
  int lm = l & 15;   // column: query m
  int lg = l >> 4;   // lane group
  int h = blockIdx.x >> 8;
  int mt = blockIdx.x & 255;
  int m0 = mt * 16;
  int m = m0 + lm;
  int xm = m & 63, ym = m >> 6;
  float ex = (xm + 0.5f) * (63.0f / 64.0f) - 31.5f;
  float ey = (ym + 0.5f) * (63.0f / 64.0f) - 31.5f;
  const char* tabb = (const char*)(tpad2 + (size_t)h * 33282);  // 16641 float2 per head
  const float* cbase = cxy + (size_t)(h >> 1) * HW * 2;

  short8 qf = *(const short8*)(qt + ((size_t)(h * HW + m) * 32 + 8 * lg));

  f32x4 oA = {0.f, 0.f, 0.f, 0.f};
  f32x4 oB = {0.f, 0.f, 0.f, 0.f};
  float m_run = -3.0e38f, l_run = 0.f;

  for (int it = 0; it < 32; ++it) {
    int n0 = (it * 4 + w) * 32;
    short8 ka = *(const short8*)(kt + ((size_t)(h * HW + n0 + lm) * 32 + 8 * lg));
    short8 kb = *(const short8*)(kt + ((size_t)(h * HW + n0 + 16 + lm) * 32 + 8 * lg));
    f32x4 z = {0.f, 0.f, 0.f, 0.f};
    f32x4 s0 = __builtin_amdgcn_mfma_f32_16x16x32_bf16(ka, qf, z, 0, 0, 0);
    f32x4 s1 = __builtin_amdgcn_mfma_f32_16x16x32_bf16(kb, qf, z, 0, 0, 0);
    short8 va = *(const short8*)(vbuf + ((size_t)(h * 32 + lm) * HW + n0 + 8 * lg));
    short8 vb = *(const short8*)(vbuf + ((size_t)(h * 32 + 16 + lm) * HW + n0 + 8 * lg));

    float sv[8];
    #pragma unroll
    for (int t = 0; t < 2; ++t) {
      #pragma unroll
      for (int r = 0; r < 4; ++r) {
        int nl = 16 * t + 4 * lg + r;
        float2 cc = *(const float2*)(cbase + (size_t)(n0 + nl) * 2);
        float gx = ex + cc.x, gy = ey + cc.y;   // always in-bounds of padded table
        float xf = floorf(gx), yf = floorf(gy);
        float fx = gx - xf, fy = gy - yf;
        int xi = (int)xf, yi = (int)yf;
        unsigned off = (unsigned)(yi * 1032 + (xi << 3));   // row stride 129*8
        f32x4u tv = *(const f32x4u*)(tabb + off);           // {a00, a10, a01, a11}
        float ly0 = tv[0] + fy * (tv[1] - tv[0]);
        float ly1 = tv[2] + fy * (tv[3] - tv[2]);
        float qk = t ? s1[r] : s0[r];
        sv[4 * t + r] = qk + (ly0 + fx * (ly1 - ly0));
      }
    }
    // per-query-column softmax over this 32-n tile
    float tmax = sv[0];
    #pragma unroll
    for (int i = 1; i < 8; ++i) tmax = fmaxf(tmax, sv[i]);
    tmax = fmaxf(tmax, __shfl_xor(tmax, 16));
    tmax = fmaxf(tmax, __shfl_xor(tmax, 32));
    float mnew = fmaxf(m_run, tmax);
    float alpha = __builtin_amdgcn_exp2f(m_run - mnew);
    float p[8]; float ps = 0.f;
    #pragma unroll
    for (int i = 0; i < 8; ++i) { p[i] = __builtin_amdgcn_exp2f(sv[i] - mnew); ps += p[i]; }
    ps += __shfl_xor(ps, 16);
    ps += __shfl_xor(ps, 32);
    l_run = l_run * alpha + ps;
    m_run = mnew;
    oA *= alpha;
    oB *= alpha;
    unsigned int w0 = (unsigned int)bf16b(p[0]) | ((unsigned int)bf16b(p[1]) << 16);
    unsigned int w1 = (unsigned int)bf16b(p[2]) | ((unsigned int)bf16b(p[3]) << 16);
    unsigned int w2 = (unsigned int)bf16b(p[4]) | ((unsigned int)bf16b(p[5]) << 16);
    unsigned int w3 = (unsigned int)bf16b(p[6]) | ((unsigned int)bf16b(p[7]) << 16);
    u32x2 wa = {w0, w1}, wb = {w2, w3};
    *(u32x2*)&P_pack[w][lm][2 * lg] = wa;
    *(u32x2*)&P_pack[w][lm][8 + 2 * lg] = wb;
    u32x4 pw = *(u32x4*)&P_pack[w][lm][4 * lg];
    union { u32x4 u; short8 s; } cv; cv.u = pw;
    oA = __builtin_amdgcn_mfma_f32_16x16x32_bf16(va, cv.s, oA, 0, 0, 0);
    oB = __builtin_amdgcn_mfma_f32_16x16x32_bf16(vb, cv.s, oB, 0, 0, 0);
  }

  if (lg == 0) { red_m[w][lm] = m_run; red_l[w][lm] = l_run; }
  #pragma unroll
  for (int r = 0; r < 4; ++r) {
    red_acc[w][4 * lg + r][lm] = oA[r];
    red_acc[w][16 + 4 * lg + r][lm] = oB[r];
  }
  __syncthreads();
  #pragma unroll
  for (int rep = 0; rep < 2; ++rep) {
    int idx = tid + rep * 256;
    int cl = idx >> 4, mm = idx & 15;
    float M = fmaxf(fmaxf(red_m[0][mm], red_m[1][mm]), fmaxf(red_m[2][mm], red_m[3][mm]));
    float lsum = 0.f, osum = 0.f;
    #pragma unroll
    for (int ww = 0; ww < 4; ++ww) {
      float e = __builtin_amdgcn_exp2f(red_m[ww][mm] - M);
      lsum += red_l[ww][mm] * e;
      osum += red_acc[ww][cl][mm] * e;
    }
    att[(size_t)(h * 32 + cl) * HW + m0 + mm] = osum / lsum;
  }
}

extern "C" void kernel_launch(void* const* d_in, const int* in_sizes, int n_in,
                              void* d_out, int out_size, void* d_ws, size_t ws_size,
                              hipStream_t stream) {
  const float* x    = (const float*)d_in[0];
  const float* wq   = (const float*)d_in[1];
  const float* bq   = (const float*)d_in[2];
  const float* wk   = (const float*)d_in[3];
  const float* bk   = (const float*)d_in[4];
  const float* wv   = (const float*)d_in[5];
  const float* bv   = (const float*)d_in[6];
  const float* wdw  = (const float*)d_in[7];
  const float* bdw  = (const float*)d_in[8];
  const float* lng  = (const float*)d_in[9];
  const float* lnb  = (const float*)d_in[10];
  const float* wpw  = (const float*)d_in[11];
  const float* rpe  = (const float*)d_in[12];
  const float* wout = (const float*)d_in[13];
  const float* bout = (const float*)d_in[14];
  float* out = (float*)d_out;

  float* ws = (float*)d_ws;
  float* q_f32 = ws;                                        // 4MB (reused as xs)
  float* o_f32 = ws + (1 << 20);                            // 4MB (reused as att)
  unsigned short* qt  = (unsigned short*)(ws + (2 << 20));  // 2MB
  unsigned short* ktp = (unsigned short*)(ws + ((2 << 20) + (1 << 19)));  // 2MB
  unsigned short* vbp = (unsigned short*)(ws + (3 << 20));  // 2MB
  float* pos  = ws + ((3 << 20) + (1 << 19));               // 128KB
  float* cxy  = pos + 32768;                                // 128KB
  float* tab2 = cxy + 32768;                                // 8*16641*2*4 = 1.06MB

  gemm256<<<256, 256, 0, stream>>>(wq, bq, x, q_f32, qt, nullptr, SCALE * LOG2E);
  build_rpe2_kernel<<<521, 256, 0, stream>>>(rpe, tab2);
  dwconv_kernel<<<4096, 256, 0, stream>>>(q_f32, wdw, bdw, o_f32);
  ln_offset_kernel<<<4096, 256, 0, stream>>>(o_f32, lng, lnb, wpw, pos, cxy);
  sample_kernel<<<256, 256, 0, stream>>>(x, pos, q_f32);    // q_f32 := xs
  gemm256<<<256, 256, 0, stream>>>(wk, bk, q_f32, nullptr, ktp, nullptr, 1.0f);
  gemm256<<<256, 256, 0, stream>>>(wv, bv, q_f32, nullptr, nullptr, vbp, 1.0f);
  attn_kernel<<<2048, 256, 0, stream>>>(qt, ktp, vbp, cxy, tab2, o_f32);  // o_f32 := att
  gemm256<<<256, 256, 0, stream>>>(wout, bout, o_f32, out, nullptr, nullptr, 1.0f);
}

// Round 6
// 339.199 us; speedup vs baseline: 1.4344x; 1.0982x over previous
//
#include <hip/hip_runtime.h>
#include <hip/hip_bf16.h>
#include <math.h>

#define HW 4096
#define SCALE 0.17677669529663687f
#define LOG2E 1.4426950408889634f

typedef __attribute__((ext_vector_type(8))) short short8;
typedef __attribute__((ext_vector_type(4))) float f32x4;
typedef __attribute__((ext_vector_type(4), aligned(4))) float f32x4u;
typedef __attribute__((ext_vector_type(4))) unsigned int u32x4;
typedef __attribute__((ext_vector_type(2))) unsigned int u32x2;

static __device__ __forceinline__ unsigned short bf16b(float f) {
  __hip_bfloat16 h = __float2bfloat16(f);
  return *reinterpret_cast<unsigned short*>(&h);
}

// ---- GEMM: Y[256][4096] = W @ X + b. W via scalar (s_load) path, X via float2.
__global__ __launch_bounds__(256) void gemm256(const float* __restrict__ W,
                                               const float* __restrict__ bias,
                                               const float* __restrict__ X,
                                               float* __restrict__ Yf,
                                               unsigned short* __restrict__ Yt,
                                               unsigned short* __restrict__ Yv,
                                               float sc) {
  int tid = threadIdx.x;
  int o0 = (blockIdx.x >> 3) * 8;
  int p = (blockIdx.x & 7) * 512 + tid * 2;
  const float* Wb = W + o0 * 256;
  float ax[8], ay[8];
  #pragma unroll
  for (int i = 0; i < 8; ++i) { ax[i] = 0.f; ay[i] = 0.f; }
  #pragma unroll 4
  for (int c = 0; c < 256; ++c) {
    float2 xv = *(const float2*)(X + c * HW + p);
    #pragma unroll
    for (int i = 0; i < 8; ++i) {
      float wv = Wb[i * 256 + c];
      ax[i] += wv * xv.x;
      ay[i] += wv * xv.y;
    }
  }
  float rx[8], ry[8];
  #pragma unroll
  for (int i = 0; i < 8; ++i) {
    float b = bias[o0 + i];
    rx[i] = ax[i] + b;
    ry[i] = ay[i] + b;
  }
  if (Yf) {
    #pragma unroll
    for (int i = 0; i < 8; ++i) {
      float2 st = {rx[i], ry[i]};
      *(float2*)(Yf + (size_t)(o0 + i) * HW + p) = st;
    }
  }
  if (Yt) {
    int h = o0 >> 5, c0 = o0 & 31;
    u32x4 pk0, pk1;
    #pragma unroll
    for (int j = 0; j < 4; ++j) {
      pk0[j] = (unsigned int)bf16b(rx[2 * j] * sc) | ((unsigned int)bf16b(rx[2 * j + 1] * sc) << 16);
      pk1[j] = (unsigned int)bf16b(ry[2 * j] * sc) | ((unsigned int)bf16b(ry[2 * j + 1] * sc) << 16);
    }
    *(u32x4*)(Yt + ((size_t)(h * HW + p) * 32 + c0)) = pk0;
    *(u32x4*)(Yt + ((size_t)(h * HW + p + 1) * 32 + c0)) = pk1;
  }
  if (Yv) {
    #pragma unroll
    for (int i = 0; i < 8; ++i) {
      unsigned int pk = (unsigned int)bf16b(rx[i]) | ((unsigned int)bf16b(ry[i]) << 16);
      *(unsigned int*)(Yv + (size_t)(o0 + i) * HW + p) = pk;
    }
  }
}

// ---- depthwise 9x9 conv ----
__global__ __launch_bounds__(256) void dwconv_kernel(const float* __restrict__ q,
                                                     const float* __restrict__ wdw,
                                                     const float* __restrict__ bdw,
                                                     float* __restrict__ o) {
  int lane = threadIdx.x & 63;
  int wave = threadIdx.x >> 6;
  int bid = blockIdx.x;
  int y4 = bid & 15; int c = (bid >> 4) & 63; int g = bid >> 10;
  int y = y4 * 4 + wave;
  int x = lane;
  const float* qc = q + (g * 64 + c) * HW;
  float acc = bdw[c];
  #pragma unroll
  for (int ky = 0; ky < 9; ++ky) {
    int yy = y + ky - 4;
    if (yy < 0 || yy > 63) continue;
    #pragma unroll
    for (int kx = 0; kx < 9; ++kx) {
      int xx = x + kx - 4;
      if (xx < 0 || xx > 63) continue;
      acc += wdw[c * 81 + ky * 9 + kx] * qc[yy * 64 + xx];
    }
  }
  o[(g * 64 + c) * HW + y * 64 + x] = acc;
}

// ---- LN + GELU + pointwise + tanh -> pos (y,x) and padded-coord constants cxy ----
__global__ __launch_bounds__(256) void ln_offset_kernel(const float* __restrict__ o,
                                                        const float* __restrict__ ln_g,
                                                        const float* __restrict__ ln_b,
                                                        const float* __restrict__ wpw,
                                                        float* __restrict__ pos,
                                                        float* __restrict__ cxy) {
  int wave = threadIdx.x >> 6;
  int c = threadIdx.x & 63;
  int bid = blockIdx.x;
  int xc = bid & 15; int y = (bid >> 4) & 63; int g = bid >> 10;
  int x = xc * 4 + wave;
  int p = y * 64 + x;
  float v = o[(g * 64 + c) * HW + p];
  float s = v, s2 = v * v;
  #pragma unroll
  for (int m = 32; m; m >>= 1) { s += __shfl_xor(s, m); s2 += __shfl_xor(s2, m); }
  float mu = s * (1.f / 64.f);
  float var = s2 * (1.f / 64.f) - mu * mu;
  float nv = (v - mu) * rsqrtf(var + 1e-5f) * ln_g[c] + ln_b[c];
  nv = 0.5f * nv * (1.f + erff(nv * 0.70710678118654752f));
  float t0 = wpw[c] * nv, t1 = wpw[64 + c] * nv;
  #pragma unroll
  for (int m = 32; m; m >>= 1) { t0 += __shfl_xor(t0, m); t1 += __shfl_xor(t1, m); }
  if (c == 0) {
    float offy = tanhf(t0) * (2.0f / 64.0f);
    float offx = tanhf(t1) * (2.0f / 64.0f);
    float py = offy + (y + 0.5f) * (2.f / 64.f) - 1.f;
    float px = offx + (x + 0.5f) * (2.f / 64.f) - 1.f;
    pos[(g * HW + p) * 2 + 0] = py;
    pos[(g * HW + p) * 2 + 1] = px;
    cxy[(g * HW + p) * 2 + 0] = 64.0f - 31.5f * px;
    cxy[(g * HW + p) * 2 + 1] = 64.0f - 31.5f * py;
  }
}

// ---- bilinear sample of x at pos -> xs[256][4096] ----
__global__ __launch_bounds__(256) void sample_kernel(const float* __restrict__ x,
                                                     const float* __restrict__ pos,
                                                     float* __restrict__ xs) {
  int bid = blockIdx.x;
  int cc = bid & 3; int nt = (bid >> 2) & 15; int g = bid >> 6;
  int n = nt * 256 + threadIdx.x;
  float py = pos[(g * HW + n) * 2 + 0];
  float px = pos[(g * HW + n) * 2 + 1];
  float gx = (px + 1.f) * 31.5f;
  float gy = (py + 1.f) * 31.5f;
  float xf = floorf(gx), yf = floorf(gy);
  int xi = (int)xf, yi = (int)yf;
  float fx = gx - xf, fy = gy - yf;
  int x0c = min(max(xi, 0), 63), x1c = min(max(xi + 1, 0), 63);
  int y0c = min(max(yi, 0), 63), y1c = min(max(yi + 1, 0), 63);
  float wx0 = ((unsigned)xi <= 63u) ? (1.f - fx) : 0.f;
  float wx1 = ((unsigned)(xi + 1) <= 63u) ? fx : 0.f;
  float wy0 = ((unsigned)yi <= 63u) ? (1.f - fy) : 0.f;
  float wy1 = ((unsigned)(yi + 1) <= 63u) ? fy : 0.f;
  #pragma unroll 4
  for (int ci = 0; ci < 16; ++ci) {
    int c = cc * 16 + ci;
    const float* xp = x + (g * 64 + c) * HW;
    float vsum = wy0 * (wx0 * xp[y0c * 64 + x0c] + wx1 * xp[y0c * 64 + x1c]) +
                 wy1 * (wx0 * xp[y1c * 64 + x0c] + wx1 * xp[y1c * 64 + x1c]);
    xs[(g * 64 + c) * HW + n] = vsum;
  }
}

// ---- build interleaved-row, zero-padded, log2e-scaled RPE tables ----
__global__ __launch_bounds__(256) void build_rpe2_kernel(const float* __restrict__ rpe,
                                                         float* __restrict__ tab2) {
  int idx = blockIdx.x * 256 + threadIdx.x;
  if (idx >= 8 * 16641) return;
  int h = idx / 16641; int r = idx - h * 16641;
  int y = r / 129, x = r - y * 129;
  float v0 = 0.f, v1 = 0.f;
  if (x >= 1 && x <= 127) {
    if (y >= 1 && y <= 127) v0 = rpe[(h * 127 + (y - 1)) * 127 + (x - 1)] * LOG2E;
    if (y + 1 >= 1 && y + 1 <= 127) v1 = rpe[(h * 127 + y) * 127 + (x - 1)] * LOG2E;
  }
  float2 v = {v0, v1};
  *(float2*)(tab2 + (size_t)idx * 2) = v;
}

// ---- fused attention: 1 head/block, packed-corner gather, pipelined cxy, exp2 softmax ----
__global__ __launch_bounds__(256, 4) void attn_kernel(const unsigned short* __restrict__ qt,
                                                      const unsigned short* __restrict__ kt,
                                                      const unsigned short* __restrict__ vbuf,
                                                      const float* __restrict__ cxy,
                                                      const float* __restrict__ tpad2,
                                                      float* __restrict__ att) {
  __shared__ __align__(16) unsigned int P_pack[4][16][20];
  __shared__ float red_m[4][16];
  __shared__ float red_l[4][16];
  __shared__ float red_acc[4][32][16];

  int tid = threadIdx.x;
  int w = tid >> 6;
  int l = tid & 63;
  int lm = l & 15;   // column: query m
  int lg = l >> 4;   // lane group
  int h = blockIdx.x >> 8;
  int mt = blockIdx.x & 255;
  int m0 = mt * 16;
  int m = m0 + lm;
  int xm = m & 63, ym = m >> 6;
  float ex = (xm + 0.5f) * (63.0f / 64.0f) - 31.5f;
  float ey = (ym + 0.5f) * (63.0f / 64.0f) - 31.5f;
  const char* tabb = (const char*)(tpad2 + (size_t)h * 33282);
  const float* cbase = cxy + (size_t)(h >> 1) * HW * 2;

  short8 qf = *(const short8*)(qt + ((size_t)(h * HW + m) * 32 + 8 * lg));

  f32x4 oA = {0.f, 0.f, 0.f, 0.f};
  f32x4 oB = {0.f, 0.f, 0.f, 0.f};
  float m_run = -3.0e38f, l_run = 0.f;

  // preload cxy for it=0 (software pipeline, one iteration ahead)
  float2 ccv[8];
  #pragma unroll
  for (int i = 0; i < 8; ++i) {
    int nl = 16 * (i >> 2) + 4 * lg + (i & 3);
    ccv[i] = *(const float2*)(cbase + (size_t)(w * 32 + nl) * 2);
  }

  for (int it = 0; it < 32; ++it) {
    int n0 = (it * 4 + w) * 32;
    short8 ka = *(const short8*)(kt + ((size_t)(h * HW + n0 + lm) * 32 + 8 * lg));
    short8 kb = *(const short8*)(kt + ((size_t)(h * HW + n0 + 16 + lm) * 32 + 8 * lg));
    f32x4 z = {0.f, 0.f, 0.f, 0.f};
    f32x4 s0 = __builtin_amdgcn_mfma_f32_16x16x32_bf16(ka, qf, z, 0, 0, 0);
    f32x4 s1 = __builtin_amdgcn_mfma_f32_16x16x32_bf16(kb, qf, z, 0, 0, 0);
    short8 va = *(const short8*)(vbuf + ((size_t)(h * 32 + lm) * HW + n0 + 8 * lg));
    short8 vb = *(const short8*)(vbuf + ((size_t)(h * 32 + 16 + lm) * HW + n0 + 8 * lg));

    // issue next iteration's cxy loads NOW (independent of current work)
    int n0n = (((it + 1) & 31) * 4 + w) * 32;
    float2 ccn[8];
    #pragma unroll
    for (int i = 0; i < 8; ++i) {
      int nl = 16 * (i >> 2) + 4 * lg + (i & 3);
      ccn[i] = *(const float2*)(cbase + (size_t)(n0n + nl) * 2);
    }

    float sv[8];
    #pragma unroll
    for (int i = 0; i < 8; ++i) {
      float gx = ex + ccv[i].x, gy = ey + ccv[i].y;   // in-bounds of padded table
      float xf = floorf(gx), yf = floorf(gy);
      float fx = gx - xf, fy = gy - yf;
      int xi = (int)xf, yi = (int)yf;
      unsigned off = (unsigned)(yi * 1032 + (xi << 3));   // row stride 129*8
      f32x4u tv = *(const f32x4u*)(tabb + off);           // {a00, a10, a01, a11}
      float ly0 = tv[0] + fy * (tv[1] - tv[0]);
      float ly1 = tv[2] + fy * (tv[3] - tv[2]);
      float qk = (i < 4) ? s0[i & 3] : s1[i & 3];
      sv[i] = qk + (ly0 + fx * (ly1 - ly0));
    }
    // per-query-column softmax over this 32-n tile
    float tmax = sv[0];
    #pragma unroll
    for (int i = 1; i < 8; ++i) tmax = fmaxf(tmax, sv[i]);
    tmax = fmaxf(tmax, __shfl_xor(tmax, 16));
    tmax = fmaxf(tmax, __shfl_xor(tmax, 32));
    float mnew = fmaxf(m_run, tmax);
    float alpha = __builtin_amdgcn_exp2f(m_run - mnew);
    float p[8]; float ps = 0.f;
    #pragma unroll
    for (int i = 0; i < 8; ++i) { p[i] = __builtin_amdgcn_exp2f(sv[i] - mnew); ps += p[i]; }
    ps += __shfl_xor(ps, 16);
    ps += __shfl_xor(ps, 32);
    l_run = l_run * alpha + ps;
    m_run = mnew;
    oA *= alpha;
    oB *= alpha;
    unsigned int w0 = (unsigned int)bf16b(p[0]) | ((unsigned int)bf16b(p[1]) << 16);
    unsigned int w1 = (unsigned int)bf16b(p[2]) | ((unsigned int)bf16b(p[3]) << 16);
    unsigned int w2 = (unsigned int)bf16b(p[4]) | ((unsigned int)bf16b(p[5]) << 16);
    unsigned int w3 = (unsigned int)bf16b(p[6]) | ((unsigned int)bf16b(p[7]) << 16);
    u32x2 wa = {w0, w1}, wb = {w2, w3};
    *(u32x2*)&P_pack[w][lm][2 * lg] = wa;
    *(u32x2*)&P_pack[w][lm][8 + 2 * lg] = wb;
    u32x4 pw = *(u32x4*)&P_pack[w][lm][4 * lg];
    union { u32x4 u; short8 s; } cv; cv.u = pw;
    oA = __builtin_amdgcn_mfma_f32_16x16x32_bf16(va, cv.s, oA, 0, 0, 0);
    oB = __builtin_amdgcn_mfma_f32_16x16x32_bf16(vb, cv.s, oB, 0, 0, 0);
    #pragma unroll
    for (int i = 0; i < 8; ++i) ccv[i] = ccn[i];
  }

  if (lg == 0) { red_m[w][lm] = m_run; red_l[w][lm] = l_run; }
  #pragma unroll
  for (int r = 0; r < 4; ++r) {
    red_acc[w][4 * lg + r][lm] = oA[r];
    red_acc[w][16 + 4 * lg + r][lm] = oB[r];
  }
  __syncthreads();
  #pragma unroll
  for (int rep = 0; rep < 2; ++rep) {
    int idx = tid + rep * 256;
    int cl = idx >> 4, mm = idx & 15;
    float M = fmaxf(fmaxf(red_m[0][mm], red_m[1][mm]), fmaxf(red_m[2][mm], red_m[3][mm]));
    float lsum = 0.f, osum = 0.f;
    #pragma unroll
    for (int ww = 0; ww < 4; ++ww) {
      float e = __builtin_amdgcn_exp2f(red_m[ww][mm] - M);
      lsum += red_l[ww][mm] * e;
      osum += red_acc[ww][cl][mm] * e;
    }
    att[(size_t)(h * 32 + cl) * HW + m0 + mm] = osum / lsum;
  }
}

extern "C" void kernel_launch(void* const* d_in, const int* in_sizes, int n_in,
                              void* d_out, int out_size, void* d_ws, size_t ws_size,
                              hipStream_t stream) {
  const float* x    = (const float*)d_in[0];
  const float* wq   = (const float*)d_in[1];
  const float* bq   = (const float*)d_in[2];
  const float* wk   = (const float*)d_in[3];
  const float* bk   = (const float*)d_in[4];
  const float* wv   = (const float*)d_in[5];
  const float* bv   = (const float*)d_in[6];
  const float* wdw  = (const float*)d_in[7];
  const float* bdw  = (const float*)d_in[8];
  const float* lng  = (const float*)d_in[9];
  const float* lnb  = (const float*)d_in[10];
  const float* wpw  = (const float*)d_in[11];
  const float* rpe  = (const float*)d_in[12];
  const float* wout = (const float*)d_in[13];
  const float* bout = (const float*)d_in[14];
  float* out = (float*)d_out;

  float* ws = (float*)d_ws;
  float* q_f32 = ws;                                        // 4MB (reused as xs)
  float* o_f32 = ws + (1 << 20);                            // 4MB (reused as att)
  unsigned short* qt  = (unsigned short*)(ws + (2 << 20));  // 2MB
  unsigned short* ktp = (unsigned short*)(ws + ((2 << 20) + (1 << 19)));  // 2MB
  unsigned short* vbp = (unsigned short*)(ws + (3 << 20));  // 2MB
  float* pos  = ws + ((3 << 20) + (1 << 19));               // 128KB
  float* cxy  = pos + 32768;                                // 128KB
  float* tab2 = cxy + 32768;                                // 1.06MB

  gemm256<<<256, 256, 0, stream>>>(wq, bq, x, q_f32, qt, nullptr, SCALE * LOG2E);
  build_rpe2_kernel<<<521, 256, 0, stream>>>(rpe, tab2);
  dwconv_kernel<<<4096, 256, 0, stream>>>(q_f32, wdw, bdw, o_f32);
  ln_offset_kernel<<<4096, 256, 0, stream>>>(o_f32, lng, lnb, wpw, pos, cxy);
  sample_kernel<<<256, 256, 0, stream>>>(x, pos, q_f32);    // q_f32 := xs
  gemm256<<<256, 256, 0, stream>>>(wk, bk, q_f32, nullptr, ktp, nullptr, 1.0f);
  gemm256<<<256, 256, 0, stream>>>(wv, bv, q_f32, nullptr, nullptr, vbp, 1.0f);
  attn_kernel<<<2048, 256, 0, stream>>>(qt, ktp, vbp, cxy, tab2, o_f32);  // o_f32 := att
  gemm256<<<256, 256, 0, stream>>>(wout, bout, o_f32, out, nullptr, nullptr, 1.0f);
}

// Round 7
// 328.728 us; speedup vs baseline: 1.4801x; 1.0319x over previous
//
#include <hip/hip_runtime.h>
#include <hip/hip_bf16.h>
#include <math.h>

#define HW 4096
#define SCALE 0.17677669529663687f
#define LOG2E 1.4426950408889634f

typedef __attribute__((ext_vector_type(8))) short short8;
typedef __attribute__((ext_vector_type(4))) float f32x4;
typedef __attribute__((ext_vector_type(4), aligned(4))) float f32x4u;
typedef __attribute__((ext_vector_type(4))) unsigned int u32x4;
typedef __attribute__((ext_vector_type(2))) unsigned int u32x2;

static __device__ __forceinline__ unsigned short bf16b(float f) {
  __hip_bfloat16 h = __float2bfloat16(f);
  return *reinterpret_cast<unsigned short*>(&h);
}

// ---- GEMM: Y[256][4096] = W @ X + b. W via scalar (s_load) path, X via float2.
__global__ __launch_bounds__(256) void gemm256(const float* __restrict__ W,
                                               const float* __restrict__ bias,
                                               const float* __restrict__ X,
                                               float* __restrict__ Yf,
                                               unsigned short* __restrict__ Yt,
                                               unsigned short* __restrict__ Yv,
                                               float sc) {
  int tid = threadIdx.x;
  int o0 = (blockIdx.x >> 3) * 8;
  int p = (blockIdx.x & 7) * 512 + tid * 2;
  const float* Wb = W + o0 * 256;
  float ax[8], ay[8];
  #pragma unroll
  for (int i = 0; i < 8; ++i) { ax[i] = 0.f; ay[i] = 0.f; }
  #pragma unroll 4
  for (int c = 0; c < 256; ++c) {
    float2 xv = *(const float2*)(X + c * HW + p);
    #pragma unroll
    for (int i = 0; i < 8; ++i) {
      float wv = Wb[i * 256 + c];
      ax[i] += wv * xv.x;
      ay[i] += wv * xv.y;
    }
  }
  float rx[8], ry[8];
  #pragma unroll
  for (int i = 0; i < 8; ++i) {
    float b = bias[o0 + i];
    rx[i] = ax[i] + b;
    ry[i] = ay[i] + b;
  }
  if (Yf) {
    #pragma unroll
    for (int i = 0; i < 8; ++i) {
      float2 st = {rx[i], ry[i]};
      *(float2*)(Yf + (size_t)(o0 + i) * HW + p) = st;
    }
  }
  if (Yt) {
    int h = o0 >> 5, c0 = o0 & 31;
    u32x4 pk0, pk1;
    #pragma unroll
    for (int j = 0; j < 4; ++j) {
      pk0[j] = (unsigned int)bf16b(rx[2 * j] * sc) | ((unsigned int)bf16b(rx[2 * j + 1] * sc) << 16);
      pk1[j] = (unsigned int)bf16b(ry[2 * j] * sc) | ((unsigned int)bf16b(ry[2 * j + 1] * sc) << 16);
    }
    *(u32x4*)(Yt + ((size_t)(h * HW + p) * 32 + c0)) = pk0;
    *(u32x4*)(Yt + ((size_t)(h * HW + p + 1) * 32 + c0)) = pk1;
  }
  if (Yv) {
    #pragma unroll
    for (int i = 0; i < 8; ++i) {
      unsigned int pk = (unsigned int)bf16b(rx[i]) | ((unsigned int)bf16b(ry[i]) << 16);
      *(unsigned int*)(Yv + (size_t)(o0 + i) * HW + p) = pk;
    }
  }
}

// ---- depthwise 9x9 conv: 8 y-outputs per thread, 16-row sliding window ----
__global__ __launch_bounds__(256) void dwconv_kernel(const float* __restrict__ q,
                                                     const float* __restrict__ wdw,
                                                     const float* __restrict__ bdw,
                                                     float* __restrict__ o) {
  int x = threadIdx.x & 63;
  int w = threadIdx.x >> 6;
  int bid = blockIdx.x;               // g*128 + c*2 + half
  int half = bid & 1; int c = (bid >> 1) & 63; int g = bid >> 7;
  int y0 = half * 32 + w * 8;
  const float* qc = q + (g * 64 + c) * HW;
  const float* wc = wdw + c * 81;
  float b = bdw[c];
  float acc[8];
  #pragma unroll
  for (int i = 0; i < 8; ++i) acc[i] = b;
  #pragma unroll
  for (int r = 0; r < 16; ++r) {
    int yy = y0 - 4 + r;
    bool rowok = (unsigned)yy <= 63u;
    int yc = min(max(yy, 0), 63);
    float v[9];
    #pragma unroll
    for (int kx = 0; kx < 9; ++kx) {
      int xx = x + kx - 4;
      bool ok = rowok && ((unsigned)xx <= 63u);
      int xc = min(max(xx, 0), 63);
      float lv = qc[yc * 64 + xc];
      v[kx] = ok ? lv : 0.f;
    }
    #pragma unroll
    for (int oy = 0; oy < 8; ++oy) {
      int ky = r - oy;
      if (ky < 0 || ky > 8) continue;   // resolved at unroll time
      #pragma unroll
      for (int kx = 0; kx < 9; ++kx)
        acc[oy] += wc[ky * 9 + kx] * v[kx];
    }
  }
  #pragma unroll
  for (int oy = 0; oy < 8; ++oy)
    o[(g * 64 + c) * HW + (y0 + oy) * 64 + x] = acc[oy];
}

// ---- LN + GELU + pointwise + tanh -> pos (y,x) and padded-coord constants cxy ----
__global__ __launch_bounds__(256) void ln_offset_kernel(const float* __restrict__ o,
                                                        const float* __restrict__ ln_g,
                                                        const float* __restrict__ ln_b,
                                                        const float* __restrict__ wpw,
                                                        float* __restrict__ pos,
                                                        float* __restrict__ cxy) {
  int wave = threadIdx.x >> 6;
  int c = threadIdx.x & 63;
  int bid = blockIdx.x;
  int xc = bid & 15; int y = (bid >> 4) & 63; int g = bid >> 10;
  int x = xc * 4 + wave;
  int p = y * 64 + x;
  float v = o[(g * 64 + c) * HW + p];
  float s = v, s2 = v * v;
  #pragma unroll
  for (int m = 32; m; m >>= 1) { s += __shfl_xor(s, m); s2 += __shfl_xor(s2, m); }
  float mu = s * (1.f / 64.f);
  float var = s2 * (1.f / 64.f) - mu * mu;
  float nv = (v - mu) * rsqrtf(var + 1e-5f) * ln_g[c] + ln_b[c];
  nv = 0.5f * nv * (1.f + erff(nv * 0.70710678118654752f));
  float t0 = wpw[c] * nv, t1 = wpw[64 + c] * nv;
  #pragma unroll
  for (int m = 32; m; m >>= 1) { t0 += __shfl_xor(t0, m); t1 += __shfl_xor(t1, m); }
  if (c == 0) {
    float offy = tanhf(t0) * (2.0f / 64.0f);
    float offx = tanhf(t1) * (2.0f / 64.0f);
    float py = offy + (y + 0.5f) * (2.f / 64.f) - 1.f;
    float px = offx + (x + 0.5f) * (2.f / 64.f) - 1.f;
    pos[(g * HW + p) * 2 + 0] = py;
    pos[(g * HW + p) * 2 + 1] = px;
    cxy[(g * HW + p) * 2 + 0] = 64.0f - 31.5f * px;
    cxy[(g * HW + p) * 2 + 1] = 64.0f - 31.5f * py;
  }
}

// ---- bilinear sample of x at pos -> xs[256][4096] ----
__global__ __launch_bounds__(256) void sample_kernel(const float* __restrict__ x,
                                                     const float* __restrict__ pos,
                                                     float* __restrict__ xs) {
  int bid = blockIdx.x;
  int cc = bid & 3; int nt = (bid >> 2) & 15; int g = bid >> 6;
  int n = nt * 256 + threadIdx.x;
  float py = pos[(g * HW + n) * 2 + 0];
  float px = pos[(g * HW + n) * 2 + 1];
  float gx = (px + 1.f) * 31.5f;
  float gy = (py + 1.f) * 31.5f;
  float xf = floorf(gx), yf = floorf(gy);
  int xi = (int)xf, yi = (int)yf;
  float fx = gx - xf, fy = gy - yf;
  int x0c = min(max(xi, 0), 63), x1c = min(max(xi + 1, 0), 63);
  int y0c = min(max(yi, 0), 63), y1c = min(max(yi + 1, 0), 63);
  float wx0 = ((unsigned)xi <= 63u) ? (1.f - fx) : 0.f;
  float wx1 = ((unsigned)(xi + 1) <= 63u) ? fx : 0.f;
  float wy0 = ((unsigned)yi <= 63u) ? (1.f - fy) : 0.f;
  float wy1 = ((unsigned)(yi + 1) <= 63u) ? fy : 0.f;
  #pragma unroll 4
  for (int ci = 0; ci < 16; ++ci) {
    int c = cc * 16 + ci;
    const float* xp = x + (g * 64 + c) * HW;
    float vsum = wy0 * (wx0 * xp[y0c * 64 + x0c] + wx1 * xp[y0c * 64 + x1c]) +
                 wy1 * (wx0 * xp[y1c * 64 + x0c] + wx1 * xp[y1c * 64 + x1c]);
    xs[(g * 64 + c) * HW + n] = vsum;
  }
}

// ---- build interleaved-row, zero-padded RPE tables, log2e-scaled, MINUS 32 ----
// tab2[h][y][x] = { pad(y,x)*LOG2E-32, pad(y+1,x)*LOG2E-32 }  (border pad = 0 -> -32)
__global__ __launch_bounds__(256) void build_rpe2_kernel(const float* __restrict__ rpe,
                                                         float* __restrict__ tab2) {
  int idx = blockIdx.x * 256 + threadIdx.x;
  if (idx >= 8 * 16641) return;
  int h = idx / 16641; int r = idx - h * 16641;
  int y = r / 129, x = r - y * 129;
  float v0 = 0.f, v1 = 0.f;
  if (x >= 1 && x <= 127) {
    if (y >= 1 && y <= 127) v0 = rpe[(h * 127 + (y - 1)) * 127 + (x - 1)] * LOG2E;
    if (y + 1 >= 1 && y + 1 <= 127) v1 = rpe[(h * 127 + y) * 127 + (x - 1)] * LOG2E;
  }
  float2 v = {v0 - 32.0f, v1 - 32.0f};
  *(float2*)(tab2 + (size_t)idx * 2) = v;
}

// ---- fused attention: fixed-scale softmax (no max tracking), packed-corner gather ----
__global__ __launch_bounds__(256, 6) void attn_kernel(const unsigned short* __restrict__ qt,
                                                      const unsigned short* __restrict__ kt,
                                                      const unsigned short* __restrict__ vbuf,
                                                      const float* __restrict__ cxy,
                                                      const float* __restrict__ tpad2,
                                                      float* __restrict__ att) {
  __shared__ __align__(16) unsigned int P_pack[4][16][20];
  __shared__ float red_l[4][16];
  __shared__ float red_acc[4][32][16];

  int tid = threadIdx.x;
  int w = tid >> 6;
  int l = tid & 63;
  int lm = l & 15;   // column: query m
  int lg = l >> 4;   // lane group
  int h = blockIdx.x >> 8;
  int mt = blockIdx.x & 255;
  int m0 = mt * 16;
  int m = m0 + lm;
  int xm = m & 63, ym = m >> 6;
  float ex = (xm + 0.5f) * (63.0f / 64.0f) - 31.5f;
  float ey = (ym + 0.5f) * (63.0f / 64.0f) - 31.5f;
  const char* tabb = (const char*)(tpad2 + (size_t)h * 33282);
  const float* cbase = cxy + (size_t)(h >> 1) * HW * 2;

  short8 qf = *(const short8*)(qt + ((size_t)(h * HW + m) * 32 + 8 * lg));

  f32x4 oA = {0.f, 0.f, 0.f, 0.f};
  f32x4 oB = {0.f, 0.f, 0.f, 0.f};
  float l_lane = 0.f;

  // preload cxy for it=0 (software pipeline, one iteration ahead)
  float2 ccv[8];
  #pragma unroll
  for (int i = 0; i < 8; ++i) {
    int nl = 16 * (i >> 2) + 4 * lg + (i & 3);
    ccv[i] = *(const float2*)(cbase + (size_t)(w * 32 + nl) * 2);
  }

  for (int it = 0; it < 32; ++it) {
    int n0 = (it * 4 + w) * 32;
    short8 ka = *(const short8*)(kt + ((size_t)(h * HW + n0 + lm) * 32 + 8 * lg));
    short8 kb = *(const short8*)(kt + ((size_t)(h * HW + n0 + 16 + lm) * 32 + 8 * lg));
    f32x4 z = {0.f, 0.f, 0.f, 0.f};
    f32x4 s0 = __builtin_amdgcn_mfma_f32_16x16x32_bf16(ka, qf, z, 0, 0, 0);
    f32x4 s1 = __builtin_amdgcn_mfma_f32_16x16x32_bf16(kb, qf, z, 0, 0, 0);
    short8 va = *(const short8*)(vbuf + ((size_t)(h * 32 + lm) * HW + n0 + 8 * lg));
    short8 vb = *(const short8*)(vbuf + ((size_t)(h * 32 + 16 + lm) * HW + n0 + 8 * lg));

    // issue next iteration's cxy loads NOW (independent of current work)
    int n0n = (((it + 1) & 31) * 4 + w) * 32;
    float2 ccn[8];
    #pragma unroll
    for (int i = 0; i < 8; ++i) {
      int nl = 16 * (i >> 2) + 4 * lg + (i & 3);
      ccn[i] = *(const float2*)(cbase + (size_t)(n0n + nl) * 2);
    }

    float p[8];
    #pragma unroll
    for (int i = 0; i < 8; ++i) {
      float gx = ex + ccv[i].x, gy = ey + ccv[i].y;   // in-bounds of padded table
      float xf = floorf(gx), yf = floorf(gy);
      float fx = gx - xf, fy = gy - yf;
      int xi = (int)xf, yi = (int)yf;
      unsigned off = (unsigned)(yi * 1032 + (xi << 3));   // row stride 129*8
      f32x4u tv = *(const f32x4u*)(tabb + off);           // {a00, a10, a01, a11}
      float ly0 = tv[0] + fy * (tv[1] - tv[0]);
      float ly1 = tv[2] + fy * (tv[3] - tv[2]);
      float qk = (i < 4) ? s0[i & 3] : s1[i & 3];
      // table already holds (bias*log2e - 32); softmax scale cancels in final divide
      p[i] = __builtin_amdgcn_exp2f(qk + (ly0 + fx * (ly1 - ly0)));
      l_lane += p[i];
    }
    // pack P to bf16 with single-instruction RNE pack
    unsigned int w0, w1, w2, w3;
    asm("v_cvt_pk_bf16_f32 %0, %1, %2" : "=v"(w0) : "v"(p[0]), "v"(p[1]));
    asm("v_cvt_pk_bf16_f32 %0, %1, %2" : "=v"(w1) : "v"(p[2]), "v"(p[3]));
    asm("v_cvt_pk_bf16_f32 %0, %1, %2" : "=v"(w2) : "v"(p[4]), "v"(p[5]));
    asm("v_cvt_pk_bf16_f32 %0, %1, %2" : "=v"(w3) : "v"(p[6]), "v"(p[7]));
    u32x2 wa = {w0, w1}, wb = {w2, w3};
    *(u32x2*)&P_pack[w][lm][2 * lg] = wa;
    *(u32x2*)&P_pack[w][lm][8 + 2 * lg] = wb;
    u32x4 pw = *(u32x4*)&P_pack[w][lm][4 * lg];
    union { u32x4 u; short8 s; } cv; cv.u = pw;
    oA = __builtin_amdgcn_mfma_f32_16x16x32_bf16(va, cv.s, oA, 0, 0, 0);
    oB = __builtin_amdgcn_mfma_f32_16x16x32_bf16(vb, cv.s, oB, 0, 0, 0);
    #pragma unroll
    for (int i = 0; i < 8; ++i) ccv[i] = ccn[i];
  }

  // reduce l across lane groups (same query column lm)
  l_lane += __shfl_xor(l_lane, 16);
  l_lane += __shfl_xor(l_lane, 32);
  if (lg == 0) red_l[w][lm] = l_lane;
  #pragma unroll
  for (int r = 0; r < 4; ++r) {
    red_acc[w][4 * lg + r][lm] = oA[r];
    red_acc[w][16 + 4 * lg + r][lm] = oB[r];
  }
  __syncthreads();
  #pragma unroll
  for (int rep = 0; rep < 2; ++rep) {
    int idx = tid + rep * 256;
    int cl = idx >> 4, mm = idx & 15;
    float lsum = 0.f, osum = 0.f;
    #pragma unroll
    for (int ww = 0; ww < 4; ++ww) {
      lsum += red_l[ww][mm];
      osum += red_acc[ww][cl][mm];
    }
    att[(size_t)(h * 32 + cl) * HW + m0 + mm] = osum / lsum;
  }
}

extern "C" void kernel_launch(void* const* d_in, const int* in_sizes, int n_in,
                              void* d_out, int out_size, void* d_ws, size_t ws_size,
                              hipStream_t stream) {
  const float* x    = (const float*)d_in[0];
  const float* wq   = (const float*)d_in[1];
  const float* bq   = (const float*)d_in[2];
  const float* wk   = (const float*)d_in[3];
  const float* bk   = (const float*)d_in[4];
  const float* wv   = (const float*)d_in[5];
  const float* bv   = (const float*)d_in[6];
  const float* wdw  = (const float*)d_in[7];
  const float* bdw  = (const float*)d_in[8];
  const float* lng  = (const float*)d_in[9];
  const float* lnb  = (const float*)d_in[10];
  const float* wpw  = (const float*)d_in[11];
  const float* rpe  = (const float*)d_in[12];
  const float* wout = (const float*)d_in[13];
  const float* bout = (const float*)d_in[14];
  float* out = (float*)d_out;

  float* ws = (float*)d_ws;
  float* q_f32 = ws;                                        // 4MB (reused as xs)
  float* o_f32 = ws + (1 << 20);                            // 4MB (reused as att)
  unsigned short* qt  = (unsigned short*)(ws + (2 << 20));  // 2MB
  unsigned short* ktp = (unsigned short*)(ws + ((2 << 20) + (1 << 19)));  // 2MB
  unsigned short* vbp = (unsigned short*)(ws + (3 << 20));  // 2MB
  float* pos  = ws + ((3 << 20) + (1 << 19));               // 128KB
  float* cxy  = pos + 32768;                                // 128KB
  float* tab2 = cxy + 32768;                                // 1.06MB

  gemm256<<<256, 256, 0, stream>>>(wq, bq, x, q_f32, qt, nullptr, SCALE * LOG2E);
  build_rpe2_kernel<<<521, 256, 0, stream>>>(rpe, tab2);
  dwconv_kernel<<<512, 256, 0, stream>>>(q_f32, wdw, bdw, o_f32);
  ln_offset_kernel<<<4096, 256, 0, stream>>>(o_f32, lng, lnb, wpw, pos, cxy);
  sample_kernel<<<256, 256, 0, stream>>>(x, pos, q_f32);    // q_f32 := xs
  gemm256<<<256, 256, 0, stream>>>(wk, bk, q_f32, nullptr, ktp, nullptr, 1.0f);
  gemm256<<<256, 256, 0, stream>>>(wv, bv, q_f32, nullptr, nullptr, vbp, 1.0f);
  attn_kernel<<<2048, 256, 0, stream>>>(qt, ktp, vbp, cxy, tab2, o_f32);  // o_f32 := att
  gemm256<<<256, 256, 0, stream>>>(wout, bout, o_f32, out, nullptr, nullptr, 1.0f);
}

// Round 8
// 319.228 us; speedup vs baseline: 1.5242x; 1.0298x over previous
//
#include <hip/hip_runtime.h>
#include <hip/hip_bf16.h>
#include <math.h>

#define HW 4096
#define SCALE 0.17677669529663687f
#define LOG2E 1.4426950408889634f

typedef __attribute__((ext_vector_type(8))) short short8;
typedef __attribute__((ext_vector_type(4))) float f32x4;
typedef __attribute__((ext_vector_type(4), aligned(4))) float f32x4u;
typedef __attribute__((ext_vector_type(4))) unsigned int u32x4;
typedef __attribute__((ext_vector_type(2))) unsigned int u32x2;

static __device__ __forceinline__ unsigned short bf16b(float f) {
  __hip_bfloat16 h = __float2bfloat16(f);
  return *reinterpret_cast<unsigned short*>(&h);
}

// ---- GEMM: Y[256][4096] = W @ X + b. W via scalar (s_load) path, X via float2.
__global__ __launch_bounds__(256) void gemm256(const float* __restrict__ W,
                                               const float* __restrict__ bias,
                                               const float* __restrict__ X,
                                               float* __restrict__ Yf,
                                               unsigned short* __restrict__ Yt,
                                               unsigned short* __restrict__ Yv,
                                               float sc) {
  int tid = threadIdx.x;
  int o0 = (blockIdx.x >> 3) * 8;
  int p = (blockIdx.x & 7) * 512 + tid * 2;
  const float* Wb = W + o0 * 256;
  float ax[8], ay[8];
  #pragma unroll
  for (int i = 0; i < 8; ++i) { ax[i] = 0.f; ay[i] = 0.f; }
  #pragma unroll 4
  for (int c = 0; c < 256; ++c) {
    float2 xv = *(const float2*)(X + c * HW + p);
    #pragma unroll
    for (int i = 0; i < 8; ++i) {
      float wv = Wb[i * 256 + c];
      ax[i] += wv * xv.x;
      ay[i] += wv * xv.y;
    }
  }
  float rx[8], ry[8];
  #pragma unroll
  for (int i = 0; i < 8; ++i) {
    float b = bias[o0 + i];
    rx[i] = ax[i] + b;
    ry[i] = ay[i] + b;
  }
  if (Yf) {
    #pragma unroll
    for (int i = 0; i < 8; ++i) {
      float2 st = {rx[i], ry[i]};
      *(float2*)(Yf + (size_t)(o0 + i) * HW + p) = st;
    }
  }
  if (Yt) {
    int h = o0 >> 5, c0 = o0 & 31;
    u32x4 pk0, pk1;
    #pragma unroll
    for (int j = 0; j < 4; ++j) {
      pk0[j] = (unsigned int)bf16b(rx[2 * j] * sc) | ((unsigned int)bf16b(rx[2 * j + 1] * sc) << 16);
      pk1[j] = (unsigned int)bf16b(ry[2 * j] * sc) | ((unsigned int)bf16b(ry[2 * j + 1] * sc) << 16);
    }
    *(u32x4*)(Yt + ((size_t)(h * HW + p) * 32 + c0)) = pk0;
    *(u32x4*)(Yt + ((size_t)(h * HW + p + 1) * 32 + c0)) = pk1;
  }
  if (Yv) {
    #pragma unroll
    for (int i = 0; i < 8; ++i) {
      unsigned int pk = (unsigned int)bf16b(rx[i]) | ((unsigned int)bf16b(ry[i]) << 16);
      *(unsigned int*)(Yv + (size_t)(o0 + i) * HW + p) = pk;
    }
  }
}

// ---- depthwise 9x9 conv: 8 y-outputs per thread, 16-row sliding window ----
__global__ __launch_bounds__(256) void dwconv_kernel(const float* __restrict__ q,
                                                     const float* __restrict__ wdw,
                                                     const float* __restrict__ bdw,
                                                     float* __restrict__ o) {
  int x = threadIdx.x & 63;
  int w = threadIdx.x >> 6;
  int bid = blockIdx.x;               // g*128 + c*2 + half
  int half = bid & 1; int c = (bid >> 1) & 63; int g = bid >> 7;
  int y0 = half * 32 + w * 8;
  const float* qc = q + (g * 64 + c) * HW;
  const float* wc = wdw + c * 81;
  float b = bdw[c];
  float acc[8];
  #pragma unroll
  for (int i = 0; i < 8; ++i) acc[i] = b;
  #pragma unroll
  for (int r = 0; r < 16; ++r) {
    int yy = y0 - 4 + r;
    bool rowok = (unsigned)yy <= 63u;
    int yc = min(max(yy, 0), 63);
    float v[9];
    #pragma unroll
    for (int kx = 0; kx < 9; ++kx) {
      int xx = x + kx - 4;
      bool ok = rowok && ((unsigned)xx <= 63u);
      int xc = min(max(xx, 0), 63);
      float lv = qc[yc * 64 + xc];
      v[kx] = ok ? lv : 0.f;
    }
    #pragma unroll
    for (int oy = 0; oy < 8; ++oy) {
      int ky = r - oy;
      if (ky < 0 || ky > 8) continue;   // resolved at unroll time
      #pragma unroll
      for (int kx = 0; kx < 9; ++kx)
        acc[oy] += wc[ky * 9 + kx] * v[kx];
    }
  }
  #pragma unroll
  for (int oy = 0; oy < 8; ++oy)
    o[(g * 64 + c) * HW + (y0 + oy) * 64 + x] = acc[oy];
}

// ---- LN + GELU + pointwise + tanh -> pos (y,x) and padded-coord constants cxy ----
__global__ __launch_bounds__(256) void ln_offset_kernel(const float* __restrict__ o,
                                                        const float* __restrict__ ln_g,
                                                        const float* __restrict__ ln_b,
                                                        const float* __restrict__ wpw,
                                                        float* __restrict__ pos,
                                                        float* __restrict__ cxy) {
  int wave = threadIdx.x >> 6;
  int c = threadIdx.x & 63;
  int bid = blockIdx.x;
  int xc = bid & 15; int y = (bid >> 4) & 63; int g = bid >> 10;
  int x = xc * 4 + wave;
  int p = y * 64 + x;
  float v = o[(g * 64 + c) * HW + p];
  float s = v, s2 = v * v;
  #pragma unroll
  for (int m = 32; m; m >>= 1) { s += __shfl_xor(s, m); s2 += __shfl_xor(s2, m); }
  float mu = s * (1.f / 64.f);
  float var = s2 * (1.f / 64.f) - mu * mu;
  float nv = (v - mu) * rsqrtf(var + 1e-5f) * ln_g[c] + ln_b[c];
  nv = 0.5f * nv * (1.f + erff(nv * 0.70710678118654752f));
  float t0 = wpw[c] * nv, t1 = wpw[64 + c] * nv;
  #pragma unroll
  for (int m = 32; m; m >>= 1) { t0 += __shfl_xor(t0, m); t1 += __shfl_xor(t1, m); }
  if (c == 0) {
    float offy = tanhf(t0) * (2.0f / 64.0f);
    float offx = tanhf(t1) * (2.0f / 64.0f);
    float py = offy + (y + 0.5f) * (2.f / 64.f) - 1.f;
    float px = offx + (x + 0.5f) * (2.f / 64.f) - 1.f;
    pos[(g * HW + p) * 2 + 0] = py;
    pos[(g * HW + p) * 2 + 1] = px;
    cxy[(g * HW + p) * 2 + 0] = 64.0f - 31.5f * px;
    cxy[(g * HW + p) * 2 + 1] = 64.0f - 31.5f * py;
  }
}

// ---- bilinear sample of x at pos -> xs[256][4096] ----
__global__ __launch_bounds__(256) void sample_kernel(const float* __restrict__ x,
                                                     const float* __restrict__ pos,
                                                     float* __restrict__ xs) {
  int bid = blockIdx.x;
  int cc = bid & 3; int nt = (bid >> 2) & 15; int g = bid >> 6;
  int n = nt * 256 + threadIdx.x;
  float py = pos[(g * HW + n) * 2 + 0];
  float px = pos[(g * HW + n) * 2 + 1];
  float gx = (px + 1.f) * 31.5f;
  float gy = (py + 1.f) * 31.5f;
  float xf = floorf(gx), yf = floorf(gy);
  int xi = (int)xf, yi = (int)yf;
  float fx = gx - xf, fy = gy - yf;
  int x0c = min(max(xi, 0), 63), x1c = min(max(xi + 1, 0), 63);
  int y0c = min(max(yi, 0), 63), y1c = min(max(yi + 1, 0), 63);
  float wx0 = ((unsigned)xi <= 63u) ? (1.f - fx) : 0.f;
  float wx1 = ((unsigned)(xi + 1) <= 63u) ? fx : 0.f;
  float wy0 = ((unsigned)yi <= 63u) ? (1.f - fy) : 0.f;
  float wy1 = ((unsigned)(yi + 1) <= 63u) ? fy : 0.f;
  #pragma unroll 4
  for (int ci = 0; ci < 16; ++ci) {
    int c = cc * 16 + ci;
    const float* xp = x + (g * 64 + c) * HW;
    float vsum = wy0 * (wx0 * xp[y0c * 64 + x0c] + wx1 * xp[y0c * 64 + x1c]) +
                 wy1 * (wx0 * xp[y1c * 64 + x0c] + wx1 * xp[y1c * 64 + x1c]);
    xs[(g * 64 + c) * HW + n] = vsum;
  }
}

// ---- build interleaved-row, zero-padded RPE tables, log2e-scaled, MINUS 32 ----
__global__ __launch_bounds__(256) void build_rpe2_kernel(const float* __restrict__ rpe,
                                                         float* __restrict__ tab2) {
  int idx = blockIdx.x * 256 + threadIdx.x;
  if (idx >= 8 * 16641) return;
  int h = idx / 16641; int r = idx - h * 16641;
  int y = r / 129, x = r - y * 129;
  float v0 = 0.f, v1 = 0.f;
  if (x >= 1 && x <= 127) {
    if (y >= 1 && y <= 127) v0 = rpe[(h * 127 + (y - 1)) * 127 + (x - 1)] * LOG2E;
    if (y + 1 >= 1 && y + 1 <= 127) v1 = rpe[(h * 127 + y) * 127 + (x - 1)] * LOG2E;
  }
  float2 v = {v0 - 32.0f, v1 - 32.0f};
  *(float2*)(tab2 + (size_t)idx * 2) = v;
}

// ---- fused attention: fully pipelined (kv, table gathers, cxy all 1+ iter ahead) ----
__global__ __launch_bounds__(256, 3) void attn_kernel(const unsigned short* __restrict__ qt,
                                                      const unsigned short* __restrict__ kt,
                                                      const unsigned short* __restrict__ vbuf,
                                                      const float* __restrict__ cxy,
                                                      const float* __restrict__ tpad2,
                                                      float* __restrict__ att) {
  __shared__ __align__(16) unsigned int P_pack[4][16][20];
  __shared__ float red_l[4][16];
  __shared__ float red_acc[4][32][16];

  int tid = threadIdx.x;
  int w = tid >> 6;
  int l = tid & 63;
  int lm = l & 15;   // column: query m
  int lg = l >> 4;   // lane group
  int h = blockIdx.x >> 8;
  int mt = blockIdx.x & 255;
  int m0 = mt * 16;
  int m = m0 + lm;
  int xm = m & 63, ym = m >> 6;
  float ex = (xm + 0.5f) * (63.0f / 64.0f) - 31.5f;
  float ey = (ym + 0.5f) * (63.0f / 64.0f) - 31.5f;
  const char* tabb = (const char*)(tpad2 + (size_t)h * 33282);
  const float* cbase = cxy + (size_t)(h >> 1) * HW * 2;

  short8 qf = *(const short8*)(qt + ((size_t)(h * HW + m) * 32 + 8 * lg));

  f32x4 oA = {0.f, 0.f, 0.f, 0.f};
  f32x4 oB = {0.f, 0.f, 0.f, 0.f};
  float l_lane = 0.f;

  // ---------------- prologue: fill the pipeline for it=0 ----------------
  float bias[8];    // bias for current iteration (it)
  float2 ccv[8];    // cxy for next iteration (it+1)
  short8 ka, kb, va, vb;  // K/V fragments for current iteration

  {
    float2 cc0[8];
    #pragma unroll
    for (int i = 0; i < 8; ++i) {
      int nl = 16 * (i >> 2) + 4 * lg + (i & 3);
      cc0[i] = *(const float2*)(cbase + (size_t)(w * 32 + nl) * 2);
    }
    // K/V for it=0
    int n0 = w * 32;
    ka = *(const short8*)(kt + ((size_t)(h * HW + n0 + lm) * 32 + 8 * lg));
    kb = *(const short8*)(kt + ((size_t)(h * HW + n0 + 16 + lm) * 32 + 8 * lg));
    va = *(const short8*)(vbuf + ((size_t)(h * 32 + lm) * HW + n0 + 8 * lg));
    vb = *(const short8*)(vbuf + ((size_t)(h * 32 + 16 + lm) * HW + n0 + 8 * lg));
    // gathers + lerp for it=0
    f32x4u tv[8];
    float fxs[8], fys[8];
    #pragma unroll
    for (int i = 0; i < 8; ++i) {
      float gx = ex + cc0[i].x, gy = ey + cc0[i].y;
      float xf = floorf(gx), yf = floorf(gy);
      fxs[i] = gx - xf; fys[i] = gy - yf;
      unsigned off = (unsigned)((int)yf * 1032 + ((int)xf << 3));
      tv[i] = *(const f32x4u*)(tabb + off);
    }
    // cxy for it=1
    #pragma unroll
    for (int i = 0; i < 8; ++i) {
      int nl = 16 * (i >> 2) + 4 * lg + (i & 3);
      ccv[i] = *(const float2*)(cbase + (size_t)(128 + w * 32 + nl) * 2);
    }
    #pragma unroll
    for (int i = 0; i < 8; ++i) {
      float ly0 = tv[i][0] + fys[i] * (tv[i][1] - tv[i][0]);
      float ly1 = tv[i][2] + fys[i] * (tv[i][3] - tv[i][2]);
      bias[i] = ly0 + fxs[i] * (ly1 - ly0);
    }
  }

  // ---------------- main loop ----------------
  #pragma unroll 2
  for (int it = 0; it < 32; ++it) {
    f32x4 z = {0.f, 0.f, 0.f, 0.f};
    f32x4 s0 = __builtin_amdgcn_mfma_f32_16x16x32_bf16(ka, qf, z, 0, 0, 0);
    f32x4 s1 = __builtin_amdgcn_mfma_f32_16x16x32_bf16(kb, qf, z, 0, 0, 0);

    // prefetch K/V for it+1
    int n0n = ((it + 1) & 31) * 128 + w * 32;
    short8 kan = *(const short8*)(kt + ((size_t)(h * HW + n0n + lm) * 32 + 8 * lg));
    short8 kbn = *(const short8*)(kt + ((size_t)(h * HW + n0n + 16 + lm) * 32 + 8 * lg));
    short8 van = *(const short8*)(vbuf + ((size_t)(h * 32 + lm) * HW + n0n + 8 * lg));
    short8 vbn = *(const short8*)(vbuf + ((size_t)(h * 32 + 16 + lm) * HW + n0n + 8 * lg));

    // issue table gathers for it+1 (addresses from prefetched ccv)
    f32x4u tv[8];
    float fxs[8], fys[8];
    #pragma unroll
    for (int i = 0; i < 8; ++i) {
      float gx = ex + ccv[i].x, gy = ey + ccv[i].y;
      float xf = floorf(gx), yf = floorf(gy);
      fxs[i] = gx - xf; fys[i] = gy - yf;
      unsigned off = (unsigned)((int)yf * 1032 + ((int)xf << 3));
      tv[i] = *(const f32x4u*)(tabb + off);
    }
    // load cxy for it+2
    int n0n2 = ((it + 2) & 31) * 128 + w * 32;
    float2 ccn[8];
    #pragma unroll
    for (int i = 0; i < 8; ++i) {
      int nl = 16 * (i >> 2) + 4 * lg + (i & 3);
      ccn[i] = *(const float2*)(cbase + (size_t)(n0n2 + nl) * 2);
    }

    // softmax for it (fixed scale; -32 folded into table)
    float p[8];
    #pragma unroll
    for (int i = 0; i < 8; ++i) {
      float qk = (i < 4) ? s0[i & 3] : s1[i & 3];
      p[i] = __builtin_amdgcn_exp2f(qk + bias[i]);
    }
    l_lane += ((p[0] + p[1]) + (p[2] + p[3])) + ((p[4] + p[5]) + (p[6] + p[7]));
    unsigned int w0 = (unsigned int)bf16b(p[0]) | ((unsigned int)bf16b(p[1]) << 16);
    unsigned int w1 = (unsigned int)bf16b(p[2]) | ((unsigned int)bf16b(p[3]) << 16);
    unsigned int w2 = (unsigned int)bf16b(p[4]) | ((unsigned int)bf16b(p[5]) << 16);
    unsigned int w3 = (unsigned int)bf16b(p[6]) | ((unsigned int)bf16b(p[7]) << 16);
    u32x2 wa = {w0, w1}, wb = {w2, w3};
    *(u32x2*)&P_pack[w][lm][2 * lg] = wa;
    *(u32x2*)&P_pack[w][lm][8 + 2 * lg] = wb;
    u32x4 pw = *(u32x4*)&P_pack[w][lm][4 * lg];
    union { u32x4 u; short8 s; } cv; cv.u = pw;
    oA = __builtin_amdgcn_mfma_f32_16x16x32_bf16(va, cv.s, oA, 0, 0, 0);
    oB = __builtin_amdgcn_mfma_f32_16x16x32_bf16(vb, cv.s, oB, 0, 0, 0);

    // finish bias for it+1 (consumes gathers; latency covered by softmax/MFMA above)
    #pragma unroll
    for (int i = 0; i < 8; ++i) {
      float ly0 = tv[i][0] + fys[i] * (tv[i][1] - tv[i][0]);
      float ly1 = tv[i][2] + fys[i] * (tv[i][3] - tv[i][2]);
      bias[i] = ly0 + fxs[i] * (ly1 - ly0);
    }
    ka = kan; kb = kbn; va = van; vb = vbn;
    #pragma unroll
    for (int i = 0; i < 8; ++i) ccv[i] = ccn[i];
  }

  // ---------------- epilogue: cross-wave merge ----------------
  l_lane += __shfl_xor(l_lane, 16);
  l_lane += __shfl_xor(l_lane, 32);
  if (lg == 0) red_l[w][lm] = l_lane;
  #pragma unroll
  for (int r = 0; r < 4; ++r) {
    red_acc[w][4 * lg + r][lm] = oA[r];
    red_acc[w][16 + 4 * lg + r][lm] = oB[r];
  }
  __syncthreads();
  #pragma unroll
  for (int rep = 0; rep < 2; ++rep) {
    int idx = tid + rep * 256;
    int cl = idx >> 4, mm = idx & 15;
    float lsum = 0.f, osum = 0.f;
    #pragma unroll
    for (int ww = 0; ww < 4; ++ww) {
      lsum += red_l[ww][mm];
      osum += red_acc[ww][cl][mm];
    }
    att[(size_t)(h * 32 + cl) * HW + m0 + mm] = osum / lsum;
  }
}

extern "C" void kernel_launch(void* const* d_in, const int* in_sizes, int n_in,
                              void* d_out, int out_size, void* d_ws, size_t ws_size,
                              hipStream_t stream) {
  const float* x    = (const float*)d_in[0];
  const float* wq   = (const float*)d_in[1];
  const float* bq   = (const float*)d_in[2];
  const float* wk   = (const float*)d_in[3];
  const float* bk   = (const float*)d_in[4];
  const float* wv   = (const float*)d_in[5];
  const float* bv   = (const float*)d_in[6];
  const float* wdw  = (const float*)d_in[7];
  const float* bdw  = (const float*)d_in[8];
  const float* lng  = (const float*)d_in[9];
  const float* lnb  = (const float*)d_in[10];
  const float* wpw  = (const float*)d_in[11];
  const float* rpe  = (const float*)d_in[12];
  const float* wout = (const float*)d_in[13];
  const float* bout = (const float*)d_in[14];
  float* out = (float*)d_out;

  float* ws = (float*)d_ws;
  float* q_f32 = ws;                                        // 4MB (reused as xs)
  float* o_f32 = ws + (1 << 20);                            // 4MB (reused as att)
  unsigned short* qt  = (unsigned short*)(ws + (2 << 20));  // 2MB
  unsigned short* ktp = (unsigned short*)(ws + ((2 << 20) + (1 << 19)));  // 2MB
  unsigned short* vbp = (unsigned short*)(ws + (3 << 20));  // 2MB
  float* pos  = ws + ((3 << 20) + (1 << 19));               // 128KB
  float* cxy  = pos + 32768;                                // 128KB
  float* tab2 = cxy + 32768;                                // 1.06MB

  gemm256<<<256, 256, 0, stream>>>(wq, bq, x, q_f32, qt, nullptr, SCALE * LOG2E);
  build_rpe2_kernel<<<521, 256, 0, stream>>>(rpe, tab2);
  dwconv_kernel<<<512, 256, 0, stream>>>(q_f32, wdw, bdw, o_f32);
  ln_offset_kernel<<<4096, 256, 0, stream>>>(o_f32, lng, lnb, wpw, pos, cxy);
  sample_kernel<<<256, 256, 0, stream>>>(x, pos, q_f32);    // q_f32 := xs
  gemm256<<<256, 256, 0, stream>>>(wk, bk, q_f32, nullptr, ktp, nullptr, 1.0f);
  gemm256<<<256, 256, 0, stream>>>(wv, bv, q_f32, nullptr, nullptr, vbp, 1.0f);
  attn_kernel<<<2048, 256, 0, stream>>>(qt, ktp, vbp, cxy, tab2, o_f32);  // o_f32 := att
  gemm256<<<256, 256, 0, stream>>>(wout, bout, o_f32, out, nullptr, nullptr, 1.0f);
}